// Round 1
// baseline (3784.634 us; speedup 1.0000x reference)
//
#include <hip/hip_runtime.h>
#include <math.h>

#define PP 384
#define HH 768
#define KK 4
#define BB 16
#define LL 2048
#define MM (BB*LL)   // 32768

__device__ __forceinline__ float sigmoid_fast(float x) { return 1.0f / (1.0f + __expf(-x)); }

// ---------------------------------------------------------------------------
// Repack weights into GEMM-friendly [N,K] row-major fp32 matrices.
// wh (1152x768): rows [0,384)=Wr, [384,768)=Wth, [768,1152)=Winj
// wb (768x768) : rows [0,384)=Re(B), [384,768)=Im(B)   (Bp is (P,H,2))
// wc (768x768) : cols [0,384)=Re(C), [384,768)=-Im(C)  (Cp is (H,P,2))
// ---------------------------------------------------------------------------
__global__ __launch_bounds__(256) void repack_kernel(
    const float* __restrict__ Wr, const float* __restrict__ Wth,
    const float* __restrict__ Winj, const float* __restrict__ Bp,
    const float* __restrict__ Cp,
    float* __restrict__ wh, float* __restrict__ wb, float* __restrict__ wc)
{
    int i = blockIdx.x * 256 + threadIdx.x;
    const int NH = 1152 * 768, NB = 768 * 768;
    if (i < NH) {
        int n = i / 768, k = i - n * 768;
        float v;
        if (n < 384)      v = Wr[n * 768 + k];
        else if (n < 768) v = Wth[(n - 384) * 768 + k];
        else              v = Winj[(n - 768) * 768 + k];
        wh[i] = v;
        return;
    }
    i -= NH;
    if (i < NB) {
        int n = i / 768, k = i - n * 768;
        wb[i] = (n < 384) ? Bp[n * 1536 + k * 2] : Bp[(n - 384) * 1536 + k * 2 + 1];
        return;
    }
    i -= NB;
    if (i < NB) {
        int n = i / 768, k = i - n * 768;
        wc[i] = (k < 384) ? Cp[n * 768 + k * 2] : -Cp[n * 768 + (k - 384) * 2 + 1];
    }
}

// ---------------------------------------------------------------------------
// fp32 tiled GEMM: C[M,N] = A[M,K] @ W[N,K]^T  (+ epilogue per MODE)
// MODE 0: plain      MODE 1: +bias, silu      MODE 2: + resid*Dv (residual)
// 128x128 tile, BK=8, 256 threads, 8x8 per-thread microtile.
// ---------------------------------------------------------------------------
template <int MODE>
__global__ __launch_bounds__(256) void gemm_kernel(
    const float* __restrict__ A, const float* __restrict__ W,
    float* __restrict__ C, int M, int N, int K,
    const float* __restrict__ bias,
    const float* __restrict__ resid, const float* __restrict__ Dv)
{
    __shared__ float As[8][132];
    __shared__ float Ws[8][132];
    const int tid  = threadIdx.x;
    const int row0 = blockIdx.x * 128;
    const int col0 = blockIdx.y * 128;
    const int lr = tid >> 1;          // 0..127 (tile row for loads)
    const int lc = (tid & 1) * 4;     // 0 or 4 (k-offset for loads)
    const int tm = (tid >> 4) * 8;    // 0..120 microtile row base
    const int tn = (tid & 15) * 8;    // 0..120 microtile col base

    float acc[8][8];
#pragma unroll
    for (int i = 0; i < 8; ++i)
#pragma unroll
        for (int j = 0; j < 8; ++j) acc[i][j] = 0.0f;

    const float* Aptr = A + (size_t)(row0 + lr) * K + lc;
    const float* Wptr = W + (size_t)(col0 + lr) * K + lc;

    for (int kt = 0; kt < K; kt += 8) {
        float4 av = *(const float4*)(Aptr + kt);
        float4 wv = *(const float4*)(Wptr + kt);
        __syncthreads();
        As[lc + 0][lr] = av.x; As[lc + 1][lr] = av.y;
        As[lc + 2][lr] = av.z; As[lc + 3][lr] = av.w;
        Ws[lc + 0][lr] = wv.x; Ws[lc + 1][lr] = wv.y;
        Ws[lc + 2][lr] = wv.z; Ws[lc + 3][lr] = wv.w;
        __syncthreads();
#pragma unroll
        for (int k = 0; k < 8; ++k) {
            float4 a0 = *(const float4*)&As[k][tm];
            float4 a1 = *(const float4*)&As[k][tm + 4];
            float4 b0 = *(const float4*)&Ws[k][tn];
            float4 b1 = *(const float4*)&Ws[k][tn + 4];
            float a[8] = {a0.x, a0.y, a0.z, a0.w, a1.x, a1.y, a1.z, a1.w};
            float b[8] = {b0.x, b0.y, b0.z, b0.w, b1.x, b1.y, b1.z, b1.w};
#pragma unroll
            for (int i = 0; i < 8; ++i)
#pragma unroll
                for (int j = 0; j < 8; ++j)
                    acc[i][j] = fmaf(a[i], b[j], acc[i][j]);
        }
    }

    float bv[8];
    if (MODE == 1) {
#pragma unroll
        for (int j = 0; j < 8; ++j) bv[j] = bias[col0 + tn + j];
    }
#pragma unroll
    for (int i = 0; i < 8; ++i) {
        const int r = row0 + tm + i;
        const size_t off = (size_t)r * N + col0 + tn;
        float v[8];
#pragma unroll
        for (int j = 0; j < 8; ++j) v[j] = acc[i][j];
        if (MODE == 1) {
#pragma unroll
            for (int j = 0; j < 8; ++j) {
                float x = v[j] + bv[j];
                v[j] = x * sigmoid_fast(x);
            }
        } else if (MODE == 2) {
            float4 r0 = *(const float4*)(resid + off);
            float4 r1 = *(const float4*)(resid + off + 4);
            float rr[8] = {r0.x, r0.y, r0.z, r0.w, r1.x, r1.y, r1.z, r1.w};
#pragma unroll
            for (int j = 0; j < 8; ++j) v[j] += rr[j] * Dv[col0 + tn + j];
        }
        float4 o0 = {v[0], v[1], v[2], v[3]};
        float4 o1 = {v[4], v[5], v[6], v[7]};
        *(float4*)(C + off)     = o0;
        *(float4*)(C + off + 4) = o1;
    }
}

// ---------------------------------------------------------------------------
// Causal depthwise conv (K=4) + bias + silu.  x,y: (B,L,H) fp32.
// ---------------------------------------------------------------------------
__global__ __launch_bounds__(256) void conv_silu_kernel(
    const float* __restrict__ x, const float* __restrict__ w,
    const float* __restrict__ cb, float* __restrict__ y)
{
    int idx = blockIdx.x * 256 + threadIdx.x;   // over M*H = 25165824
    if (idx >= MM * HH) return;
    int h  = idx % HH;
    int ml = idx / HH;       // b*L + l
    int l  = ml % LL;
    float acc = cb[h];
#pragma unroll
    for (int j = 0; j < KK; ++j) {
        int d = (KK - 1) - j;          // lag
        if (l - d >= 0) acc = fmaf(x[(size_t)(ml - d) * HH + h], w[h * KK + j], acc);
    }
    y[idx] = acc * sigmoid_fast(acc);
}

// ---------------------------------------------------------------------------
// D-LinOSS IMEX1 scan. One thread per (b,p) channel, sequential over L.
// heads (M,3P): [Rpre | Thpre | Injpre].  bu (M,2P): [Re | Im] (ungated).
// states (M,2P): [xRe | xIm].
// ---------------------------------------------------------------------------
__global__ __launch_bounds__(256) void scan_kernel(
    const float* __restrict__ heads, const float* __restrict__ bu,
    const float* __restrict__ r_base, const float* __restrict__ th_base,
    const float* __restrict__ dt_base, const float* __restrict__ inj,
    float* __restrict__ states)
{
    int t = blockIdx.x * 256 + threadIdx.x;     // 0..6143
    if (t >= BB * PP) return;
    int b = t / PP, p = t - b * PP;
    const float rb = r_base[p], tb = th_base[p], il = inj[p];
    const float dt = 0.02f + 0.98f / (1.0f + expf(-dt_base[p]));  // dtc = dt (>= 0.02)
    const float PIf = 3.14159265358979323846f;
    float zRe = 0.f, zIm = 0.f, xRe = 0.f, xIm = 0.f;
    const size_t m0 = (size_t)b * LL;
    for (int l = 0; l < LL; ++l) {
        const size_t m = m0 + l;
        const float Rp = heads[m * 1152 + p];
        const float Tp = heads[m * 1152 + 384 + p];
        const float Ip = heads[m * 1152 + 768 + p];
        const float b0 = bu[m * 768 + p];
        const float b1 = bu[m * 768 + 384 + p];
        // per-step coefficients (state-independent)
        const float r  = 1.0f / (1.0f + expf(-(rb + Rp)));
        const float th = PIf * tanhf(tb + Tp);
        const float ct = __cosf(th);
        const float r2 = fmaxf(r * r, 1e-8f);
        const float Ac = (r2 - 2.0f * r * ct + 1.0f) / (dt * dt * r2);
        const float Gc = (1.0f - r2) / (dt * r2);
        const float S  = 1.0f / (1.0f + dt * Gc);
        const float gate = 1.0f / (1.0f + expf(-(il + Ip)));
        const float dtA  = dt * Ac;
        const float Sdt  = S * dt;
        const float gRe = b0 * gate, gIm = b1 * gate;
        // dependent chain
        zRe = S * (zRe - dtA * xRe) + Sdt * gRe;
        zIm = S * (zIm - dtA * xIm) + Sdt * gIm;
        xRe = fmaf(dt, zRe, xRe);
        xIm = fmaf(dt, zIm, xIm);
        states[m * 768 + p]       = xRe;
        states[m * 768 + 384 + p] = xIm;
    }
}

// ---------------------------------------------------------------------------
extern "C" void kernel_launch(void* const* d_in, const int* in_sizes, int n_in,
                              void* d_out, int out_size, void* d_ws, size_t ws_size,
                              hipStream_t stream)
{
    const float* inputs  = (const float*)d_in[0];   // (B,L,H)
    const float* Wl      = (const float*)d_in[1];   // (H,H)
    const float* bl      = (const float*)d_in[2];   // (H)
    const float* conv_w  = (const float*)d_in[3];   // (H,1,K)
    const float* conv_b  = (const float*)d_in[4];   // (H)
    const float* Wr      = (const float*)d_in[5];   // (P,H)
    const float* Wth     = (const float*)d_in[6];   // (P,H)
    const float* Winj    = (const float*)d_in[7];   // (P,H)
    const float* r_base  = (const float*)d_in[8];   // (P)
    const float* th_base = (const float*)d_in[9];   // (P)
    const float* dt_base = (const float*)d_in[10];  // (P)
    const float* inj_l   = (const float*)d_in[11];  // (P)
    const float* Bp      = (const float*)d_in[12];  // (P,H,2)
    const float* Cp      = (const float*)d_in[13];  // (H,P,2)
    const float* Dv      = (const float*)d_in[14];  // (H)
    float* out = (float*)d_out;                     // (B,L,H)

    // workspace layout (floats)
    float* ws = (float*)d_ws;
    float* wh     = ws;                       // 1152*768 = 884736
    float* wb     = wh + 884736;              // 768*768  = 589824
    float* wc     = wb + 589824;              // 768*768  = 589824
    float* feats1 = wc + 589824;              // M*768 (encoder out; reused for states)
    float* heads  = feats1 + (size_t)MM * 768;  // M*1152
    float* bu     = heads + (size_t)MM * 1152;  // M*768
    float* feats  = out;                      // reuse d_out as conv-output scratch
    float* states = feats1;                   // alias (feats1 dead after conv)

    // 1. repack weights
    {
        int total = 1152 * 768 + 2 * 768 * 768;
        repack_kernel<<<(total + 255) / 256, 256, 0, stream>>>(Wr, Wth, Winj, Bp, Cp, wh, wb, wc);
    }
    // 2. encoder: feats1 = silu(inputs @ Wl^T + bl)
    gemm_kernel<1><<<dim3(MM / 128, 768 / 128), 256, 0, stream>>>(
        inputs, Wl, feats1, MM, 768, 768, bl, nullptr, nullptr);
    // 3. conv + silu: feats (in d_out)
    conv_silu_kernel<<<(MM * HH + 255) / 256, 256, 0, stream>>>(feats1, conv_w, conv_b, feats);
    // 4. selective heads: heads = feats @ [Wr;Wth;Winj]^T
    gemm_kernel<0><<<dim3(MM / 128, 1152 / 128), 256, 0, stream>>>(
        feats, wh, heads, MM, 1152, 768, nullptr, nullptr, nullptr);
    // 5. input projection: bu = inputs @ [BRe;BIm]^T
    gemm_kernel<0><<<dim3(MM / 128, 768 / 128), 256, 0, stream>>>(
        inputs, wb, bu, MM, 768, 768, nullptr, nullptr, nullptr);
    // 6. scan -> states (overwrites feats1)
    scan_kernel<<<(BB * PP + 255) / 256, 256, 0, stream>>>(
        heads, bu, r_base, th_base, dt_base, inj_l, states);
    // 7. output projection + residual: out = states @ [CRe|-CIm]^T + inputs*D
    gemm_kernel<2><<<dim3(MM / 128, 768 / 128), 256, 0, stream>>>(
        states, wc, out, MM, 768, 768, nullptr, inputs, Dv);
}

// Round 2
// 2377.171 us; speedup vs baseline: 1.5921x; 1.5921x over previous
//
#include <hip/hip_runtime.h>
#include <math.h>

#define PP 384
#define HH 768
#define KK 4
#define BB 16
#define LL 2048
#define MM (BB*LL)   // 32768
#define NCH (BB*PP)  // 6144 channels
#define NC 32        // chunks per sequence
#define CLEN (LL/NC) // 64 steps per chunk

__device__ __forceinline__ float sigmoid_fast(float x) { return 1.0f / (1.0f + __expf(-x)); }

// Per-step scalar coefficients (state-independent).
// z' = c0*z - c1*x + gdt*bu ;  x' = x + dt*z'
__device__ __forceinline__ void step_coef(float Rp, float Tp, float Ip,
    float rb, float tb, float il, float dt,
    float& c0, float& c1, float& gdt)
{
    const float PIf = 3.14159265358979323846f;
    float r  = 1.0f / (1.0f + expf(-(rb + Rp)));
    float th = PIf * tanhf(tb + Tp);
    float ct = __cosf(th);
    float r2 = fmaxf(r * r, 1e-8f);
    float Ac = (r2 - 2.0f * r * ct + 1.0f) / (dt * dt * r2);
    float Gc = (1.0f - r2) / (dt * r2);
    float S  = 1.0f / (1.0f + dt * Gc);
    float gate = 1.0f / (1.0f + expf(-(il + Ip)));
    c0 = S;
    c1 = S * (dt * Ac);
    gdt = S * dt * gate;
}

// ---------------------------------------------------------------------------
// Repack weights into GEMM-friendly [N,K] row-major fp32 matrices.
// ---------------------------------------------------------------------------
__global__ __launch_bounds__(256) void repack_kernel(
    const float* __restrict__ Wr, const float* __restrict__ Wth,
    const float* __restrict__ Winj, const float* __restrict__ Bp,
    const float* __restrict__ Cp,
    float* __restrict__ wh, float* __restrict__ wb, float* __restrict__ wc)
{
    int i = blockIdx.x * 256 + threadIdx.x;
    const int NH = 1152 * 768, NB = 768 * 768;
    if (i < NH) {
        int n = i / 768, k = i - n * 768;
        float v;
        if (n < 384)      v = Wr[n * 768 + k];
        else if (n < 768) v = Wth[(n - 384) * 768 + k];
        else              v = Winj[(n - 768) * 768 + k];
        wh[i] = v;
        return;
    }
    i -= NH;
    if (i < NB) {
        int n = i / 768, k = i - n * 768;
        wb[i] = (n < 384) ? Bp[n * 1536 + k * 2] : Bp[(n - 384) * 1536 + k * 2 + 1];
        return;
    }
    i -= NB;
    if (i < NB) {
        int n = i / 768, k = i - n * 768;
        wc[i] = (k < 384) ? Cp[n * 768 + k * 2] : -Cp[n * 768 + (k - 384) * 2 + 1];
    }
}

// ---------------------------------------------------------------------------
// fp32 tiled GEMM: C[M,N] = A[M,K] @ W[N,K]^T  (+ epilogue per MODE)
// MODE 0: plain      MODE 1: +bias, silu      MODE 2: + resid*Dv
// ---------------------------------------------------------------------------
template <int MODE>
__global__ __launch_bounds__(256) void gemm_kernel(
    const float* __restrict__ A, const float* __restrict__ W,
    float* __restrict__ C, int M, int N, int K,
    const float* __restrict__ bias,
    const float* __restrict__ resid, const float* __restrict__ Dv)
{
    __shared__ float As[8][132];
    __shared__ float Ws[8][132];
    const int tid  = threadIdx.x;
    const int row0 = blockIdx.x * 128;
    const int col0 = blockIdx.y * 128;
    const int lr = tid >> 1;
    const int lc = (tid & 1) * 4;
    const int tm = (tid >> 4) * 8;
    const int tn = (tid & 15) * 8;

    float acc[8][8];
#pragma unroll
    for (int i = 0; i < 8; ++i)
#pragma unroll
        for (int j = 0; j < 8; ++j) acc[i][j] = 0.0f;

    const float* Aptr = A + (size_t)(row0 + lr) * K + lc;
    const float* Wptr = W + (size_t)(col0 + lr) * K + lc;

    for (int kt = 0; kt < K; kt += 8) {
        float4 av = *(const float4*)(Aptr + kt);
        float4 wv = *(const float4*)(Wptr + kt);
        __syncthreads();
        As[lc + 0][lr] = av.x; As[lc + 1][lr] = av.y;
        As[lc + 2][lr] = av.z; As[lc + 3][lr] = av.w;
        Ws[lc + 0][lr] = wv.x; Ws[lc + 1][lr] = wv.y;
        Ws[lc + 2][lr] = wv.z; Ws[lc + 3][lr] = wv.w;
        __syncthreads();
#pragma unroll
        for (int k = 0; k < 8; ++k) {
            float4 a0 = *(const float4*)&As[k][tm];
            float4 a1 = *(const float4*)&As[k][tm + 4];
            float4 b0 = *(const float4*)&Ws[k][tn];
            float4 b1 = *(const float4*)&Ws[k][tn + 4];
            float a[8] = {a0.x, a0.y, a0.z, a0.w, a1.x, a1.y, a1.z, a1.w};
            float b[8] = {b0.x, b0.y, b0.z, b0.w, b1.x, b1.y, b1.z, b1.w};
#pragma unroll
            for (int i = 0; i < 8; ++i)
#pragma unroll
                for (int j = 0; j < 8; ++j)
                    acc[i][j] = fmaf(a[i], b[j], acc[i][j]);
        }
    }

    float bv[8];
    if (MODE == 1) {
#pragma unroll
        for (int j = 0; j < 8; ++j) bv[j] = bias[col0 + tn + j];
    }
#pragma unroll
    for (int i = 0; i < 8; ++i) {
        const int r = row0 + tm + i;
        const size_t off = (size_t)r * N + col0 + tn;
        float v[8];
#pragma unroll
        for (int j = 0; j < 8; ++j) v[j] = acc[i][j];
        if (MODE == 1) {
#pragma unroll
            for (int j = 0; j < 8; ++j) {
                float x = v[j] + bv[j];
                v[j] = x * sigmoid_fast(x);
            }
        } else if (MODE == 2) {
            float4 r0 = *(const float4*)(resid + off);
            float4 r1 = *(const float4*)(resid + off + 4);
            float rr[8] = {r0.x, r0.y, r0.z, r0.w, r1.x, r1.y, r1.z, r1.w};
#pragma unroll
            for (int j = 0; j < 8; ++j) v[j] += rr[j] * Dv[col0 + tn + j];
        }
        float4 o0 = {v[0], v[1], v[2], v[3]};
        float4 o1 = {v[4], v[5], v[6], v[7]};
        *(float4*)(C + off)     = o0;
        *(float4*)(C + off + 4) = o1;
    }
}

// ---------------------------------------------------------------------------
// Causal depthwise conv (K=4) + bias + silu.
// ---------------------------------------------------------------------------
__global__ __launch_bounds__(256) void conv_silu_kernel(
    const float* __restrict__ x, const float* __restrict__ w,
    const float* __restrict__ cb, float* __restrict__ y)
{
    int idx = blockIdx.x * 256 + threadIdx.x;
    if (idx >= MM * HH) return;
    int h  = idx % HH;
    int ml = idx / HH;
    int l  = ml % LL;
    float acc = cb[h];
#pragma unroll
    for (int j = 0; j < KK; ++j) {
        int d = (KK - 1) - j;
        if (l - d >= 0) acc = fmaf(x[(size_t)(ml - d) * HH + h], w[h * KK + j], acc);
    }
    y[idx] = acc * sigmoid_fast(acc);
}

// ---------------------------------------------------------------------------
// Phase B: per-(channel,chunk) affine composition over CLEN steps.
// state_after_chunk = M * state_before + v    (same M for Re/Im, diff v)
// summA[g] = {m00,m01,m10,m11}   summB[g] = {vzRe,vxRe,vzIm,vxIm}
// ---------------------------------------------------------------------------
__global__ __launch_bounds__(256) void scan_chunk_kernel(
    const float* __restrict__ heads, const float* __restrict__ bu,
    const float* __restrict__ r_base, const float* __restrict__ th_base,
    const float* __restrict__ dt_base, const float* __restrict__ inj,
    float4* __restrict__ summA, float4* __restrict__ summB)
{
    int g = blockIdx.x * 256 + threadIdx.x;     // 0 .. NC*NCH
    if (g >= NC * NCH) return;
    int t = g % NCH;
    int j = g / NCH;
    int b = t / PP, p = t - b * PP;
    const float rb = r_base[p], tb = th_base[p], il = inj[p];
    const float dt = 0.02f + 0.98f / (1.0f + expf(-dt_base[p]));
    float m00 = 1.f, m01 = 0.f, m10 = 0.f, m11 = 1.f;
    float vzR = 0.f, vxR = 0.f, vzI = 0.f, vxI = 0.f;
    const int mbase = b * LL + j * CLEN;
    for (int l = 0; l < CLEN; ++l) {
        const size_t m = (size_t)(mbase + l);
        const float Rp = heads[m * 1152 + p];
        const float Tp = heads[m * 1152 + 384 + p];
        const float Ip = heads[m * 1152 + 768 + p];
        const float b0 = bu[m * 768 + p];
        const float b1 = bu[m * 768 + 384 + p];
        float c0, c1, gdt;
        step_coef(Rp, Tp, Ip, rb, tb, il, dt, c0, c1, gdt);
        const float azR = gdt * b0, azI = gdt * b1;
        // M <- T*M
        float nm00 = c0 * m00 - c1 * m10;
        float nm01 = c0 * m01 - c1 * m11;
        m10 = fmaf(dt, nm00, m10);
        m11 = fmaf(dt, nm01, m11);
        m00 = nm00; m01 = nm01;
        // v <- T*v + b
        float nvzR = c0 * vzR - c1 * vxR + azR;
        vxR = fmaf(dt, nvzR, vxR); vzR = nvzR;
        float nvzI = c0 * vzI - c1 * vxI + azI;
        vxI = fmaf(dt, nvzI, vxI); vzI = nvzI;
    }
    summA[g] = make_float4(m00, m01, m10, m11);
    summB[g] = make_float4(vzR, vxR, vzI, vxI);
}

// ---------------------------------------------------------------------------
// Phase C: sequential scan over NC chunk summaries per channel.
// starts[j*NCH+t] = state (zR,xR,zI,xI) at the START of chunk j.
// ---------------------------------------------------------------------------
__global__ __launch_bounds__(256) void scan_mid_kernel(
    const float4* __restrict__ summA, const float4* __restrict__ summB,
    float4* __restrict__ starts)
{
    int t = blockIdx.x * 256 + threadIdx.x;
    if (t >= NCH) return;
    float zR = 0.f, xR = 0.f, zI = 0.f, xI = 0.f;
    for (int j = 0; j < NC; ++j) {
        starts[j * NCH + t] = make_float4(zR, xR, zI, xI);
        float4 Mv = summA[j * NCH + t];
        float4 Vv = summB[j * NCH + t];
        float nzR = Mv.x * zR + Mv.y * xR + Vv.x;
        float nxR = Mv.z * zR + Mv.w * xR + Vv.y;
        float nzI = Mv.x * zI + Mv.y * xI + Vv.z;
        float nxI = Mv.z * zI + Mv.w * xI + Vv.w;
        zR = nzR; xR = nxR; zI = nzI; xI = nxI;
    }
}

// ---------------------------------------------------------------------------
// Phase D: replay each chunk from its start state, writing states (M,2P).
// ---------------------------------------------------------------------------
__global__ __launch_bounds__(256) void scan_apply_kernel(
    const float* __restrict__ heads, const float* __restrict__ bu,
    const float* __restrict__ r_base, const float* __restrict__ th_base,
    const float* __restrict__ dt_base, const float* __restrict__ inj,
    const float4* __restrict__ starts, float* __restrict__ states)
{
    int g = blockIdx.x * 256 + threadIdx.x;
    if (g >= NC * NCH) return;
    int t = g % NCH;
    int j = g / NCH;
    int b = t / PP, p = t - b * PP;
    const float rb = r_base[p], tb = th_base[p], il = inj[p];
    const float dt = 0.02f + 0.98f / (1.0f + expf(-dt_base[p]));
    float4 s0 = starts[j * NCH + t];
    float zR = s0.x, xR = s0.y, zI = s0.z, xI = s0.w;
    const int mbase = b * LL + j * CLEN;
    for (int l = 0; l < CLEN; ++l) {
        const size_t m = (size_t)(mbase + l);
        const float Rp = heads[m * 1152 + p];
        const float Tp = heads[m * 1152 + 384 + p];
        const float Ip = heads[m * 1152 + 768 + p];
        const float b0 = bu[m * 768 + p];
        const float b1 = bu[m * 768 + 384 + p];
        float c0, c1, gdt;
        step_coef(Rp, Tp, Ip, rb, tb, il, dt, c0, c1, gdt);
        zR = c0 * zR - c1 * xR + gdt * b0;
        xR = fmaf(dt, zR, xR);
        zI = c0 * zI - c1 * xI + gdt * b1;
        xI = fmaf(dt, zI, xI);
        states[m * 768 + p]       = xR;
        states[m * 768 + 384 + p] = xI;
    }
}

// ---------------------------------------------------------------------------
extern "C" void kernel_launch(void* const* d_in, const int* in_sizes, int n_in,
                              void* d_out, int out_size, void* d_ws, size_t ws_size,
                              hipStream_t stream)
{
    const float* inputs  = (const float*)d_in[0];
    const float* Wl      = (const float*)d_in[1];
    const float* bl      = (const float*)d_in[2];
    const float* conv_w  = (const float*)d_in[3];
    const float* conv_b  = (const float*)d_in[4];
    const float* Wr      = (const float*)d_in[5];
    const float* Wth     = (const float*)d_in[6];
    const float* Winj    = (const float*)d_in[7];
    const float* r_base  = (const float*)d_in[8];
    const float* th_base = (const float*)d_in[9];
    const float* dt_base = (const float*)d_in[10];
    const float* inj_l   = (const float*)d_in[11];
    const float* Bp      = (const float*)d_in[12];
    const float* Cp      = (const float*)d_in[13];
    const float* Dv      = (const float*)d_in[14];
    float* out = (float*)d_out;

    float* ws = (float*)d_ws;
    float* wh     = ws;                                   // 1152*768
    float* wb     = wh + 884736;                          // 768*768
    float* wc     = wb + 589824;                          // 768*768
    float* feats1 = wc + 589824;                          // M*768 (encoder out; later states)
    float* heads  = feats1 + (size_t)MM * 768;            // M*1152
    float* bu     = heads + (size_t)MM * 1152;            // M*768
    float4* summA = (float4*)(bu + (size_t)MM * 768);     // NC*NCH
    float4* summB = summA + (size_t)NC * NCH;             // NC*NCH
    float4* starts= summB + (size_t)NC * NCH;             // NC*NCH
    float* feats  = out;          // reuse d_out for conv output
    float* states = feats1;       // alias (feats1 dead after conv)

    // 1. repack weights
    {
        int total = 1152 * 768 + 2 * 768 * 768;
        repack_kernel<<<(total + 255) / 256, 256, 0, stream>>>(Wr, Wth, Winj, Bp, Cp, wh, wb, wc);
    }
    // 2. encoder
    gemm_kernel<1><<<dim3(MM / 128, 768 / 128), 256, 0, stream>>>(
        inputs, Wl, feats1, MM, 768, 768, bl, nullptr, nullptr);
    // 3. conv + silu -> d_out
    conv_silu_kernel<<<(MM * HH + 255) / 256, 256, 0, stream>>>(feats1, conv_w, conv_b, feats);
    // 4. selective heads
    gemm_kernel<0><<<dim3(MM / 128, 1152 / 128), 256, 0, stream>>>(
        feats, wh, heads, MM, 1152, 768, nullptr, nullptr, nullptr);
    // 5. input projection
    gemm_kernel<0><<<dim3(MM / 128, 768 / 128), 256, 0, stream>>>(
        inputs, wb, bu, MM, 768, 768, nullptr, nullptr, nullptr);
    // 6. chunked scan: B (compose) -> C (mid) -> D (apply)
    scan_chunk_kernel<<<(NC * NCH) / 256, 256, 0, stream>>>(
        heads, bu, r_base, th_base, dt_base, inj_l, summA, summB);
    scan_mid_kernel<<<(NCH + 255) / 256, 256, 0, stream>>>(summA, summB, starts);
    scan_apply_kernel<<<(NC * NCH) / 256, 256, 0, stream>>>(
        heads, bu, r_base, th_base, dt_base, inj_l, starts, states);
    // 7. output projection + residual
    gemm_kernel<2><<<dim3(MM / 128, 768 / 128), 256, 0, stream>>>(
        states, wc, out, MM, 768, 768, nullptr, inputs, Dv);
}

// Round 5
// 836.416 us; speedup vs baseline: 4.5248x; 2.8421x over previous
//
#include <hip/hip_runtime.h>
#include <math.h>

#define PP 384
#define HH 768
#define KK 4
#define BB 16
#define LL 2048
#define MM (BB*LL)   // 32768
#define NCH (BB*PP)  // 6144
#define NC 32
#define CLEN (LL/NC) // 64

typedef __attribute__((ext_vector_type(8))) short bf16x8;
typedef __attribute__((ext_vector_type(4))) float f32x4;

__device__ __forceinline__ float sigmoid_fast(float x) { return 1.0f / (1.0f + __expf(-x)); }

__device__ __forceinline__ float bf2f(unsigned short h) {
    return __uint_as_float(((unsigned int)h) << 16);
}
__device__ __forceinline__ unsigned short f2bf(float x) {
    unsigned int u = __float_as_uint(x);
    u += 0x7fff + ((u >> 16) & 1);          // round-to-nearest-even
    return (unsigned short)(u >> 16);
}
// split x into hi (bf16) and lo (bf16 of residual): x ≈ hi + lo, err ~2^-17
__device__ __forceinline__ void split_bf(float x, unsigned short& hi, unsigned short& lo) {
    hi = f2bf(x);
    lo = f2bf(x - bf2f(hi));
}

__device__ __forceinline__ void gll16(const void* g, void* l) {
    __builtin_amdgcn_global_load_lds(
        (const __attribute__((address_space(1))) void*)g,
        (__attribute__((address_space(3))) void*)l, 16, 0, 0);
}

// Per-step scalar coefficients (state-independent).
__device__ __forceinline__ void step_coef(float Rp, float Tp, float Ip,
    float rb, float tb, float il, float dt,
    float& c0, float& c1, float& gdt)
{
    const float PIf = 3.14159265358979323846f;
    float r  = 1.0f / (1.0f + expf(-(rb + Rp)));
    float th = PIf * tanhf(tb + Tp);
    float ct = __cosf(th);
    float r2 = fmaxf(r * r, 1e-8f);
    float Ac = (r2 - 2.0f * r * ct + 1.0f) / (dt * dt * r2);
    float Gc = (1.0f - r2) / (dt * r2);
    float S  = 1.0f / (1.0f + dt * Gc);
    float gate = 1.0f / (1.0f + expf(-(il + Ip)));
    c0 = S;
    c1 = S * (dt * Ac);
    gdt = S * dt * gate;
}

// ---------------------------------------------------------------------------
// Weight repack:
//  wl hi/lo (768x768)   = Wl split
//  wh hi/lo (1152x768)  = [Wr;Wth;Winj] split
//  wb (768x768) bf16    = [BRe;BIm]
//  wc (768x768) bf16    : cols [0,384)=CRe, [384,768)=-CIm
// ---------------------------------------------------------------------------
__global__ __launch_bounds__(256) void repack_kernel(
    const float* __restrict__ Wl, const float* __restrict__ Wr,
    const float* __restrict__ Wth, const float* __restrict__ Winj,
    const float* __restrict__ Bp, const float* __restrict__ Cp,
    unsigned short* __restrict__ wlh, unsigned short* __restrict__ wll,
    unsigned short* __restrict__ whh, unsigned short* __restrict__ whl,
    unsigned short* __restrict__ wb, unsigned short* __restrict__ wc)
{
    int i = blockIdx.x * 256 + threadIdx.x;
    const int NB = 768 * 768, NHd = 1152 * 768;
    if (i < NB) { split_bf(Wl[i], wlh[i], wll[i]); return; }
    i -= NB;
    if (i < NHd) {
        int n = i / 768, k = i - n * 768;
        float v;
        if (n < 384)      v = Wr[n * 768 + k];
        else if (n < 768) v = Wth[(n - 384) * 768 + k];
        else              v = Winj[(n - 768) * 768 + k];
        split_bf(v, whh[i], whl[i]);
        return;
    }
    i -= NHd;
    if (i < NB) {
        int n = i / 768, k = i - n * 768;
        wb[i] = f2bf((n < 384) ? Bp[n * 1536 + k * 2] : Bp[(n - 384) * 1536 + k * 2 + 1]);
        return;
    }
    i -= NB;
    if (i < NB) {
        int n = i / 768, k = i - n * 768;
        wc[i] = f2bf((k < 384) ? Cp[n * 768 + k * 2] : -Cp[n * 768 + (k - 384) * 2 + 1]);
    }
}

// inputs -> hi/lo split buffers
__global__ __launch_bounds__(256) void split_convert_kernel(
    const float* __restrict__ in, unsigned short* __restrict__ outh,
    unsigned short* __restrict__ outl, int n4)
{
    int i = blockIdx.x * 256 + threadIdx.x;
    if (i >= n4) return;
    float4 a = ((const float4*)in)[i];
    ushort4 h, l;
    split_bf(a.x, h.x, l.x); split_bf(a.y, h.y, l.y);
    split_bf(a.z, h.z, l.z); split_bf(a.w, h.w, l.w);
    ((ushort4*)outh)[i] = h;
    ((ushort4*)outl)[i] = l;
}

// ---------------------------------------------------------------------------
// SPLIT-PRECISION bf16 MFMA GEMM: C = (Ah+Al)[M,768] @ ((Wh+Wl)[N,768])^T
//   = Ah*Wh + Ah*Wl + Al*Wh  (3 MFMAs, ~17-bit effective mantissa)
// 128x128 tile, BK=32, 4 waves (2x2). SMODE 0: fp32 out. SMODE 1: +bias, silu, fp32 out.
// ---------------------------------------------------------------------------
template <int SMODE>
__global__ __launch_bounds__(256) void mfma_gemm_split(
    const unsigned short* __restrict__ Ah, const unsigned short* __restrict__ Al,
    const unsigned short* __restrict__ Wh, const unsigned short* __restrict__ Wl,
    float* __restrict__ Cout, int N, const float* __restrict__ bias)
{
    constexpr int K = 768;
    __shared__ unsigned short lsAh[128 * 32];
    __shared__ unsigned short lsAl[128 * 32];
    __shared__ unsigned short lsBh[128 * 32];
    __shared__ unsigned short lsBl[128 * 32];
    const int tid  = threadIdx.x;
    const int wave = tid >> 6, lane = tid & 63;
    const int wm = wave >> 1, wn = wave & 1;
    const int row0 = blockIdx.x * 128, col0 = blockIdx.y * 128;

    const int srow = (wave << 4) + (lane >> 2);    // 0..63
    const int scol = (lane & 3) << 3;              // 0,8,16,24
    const size_t ga0 = (size_t)(row0 + srow) * K + scol;
    const size_t ga1 = (size_t)(row0 + 64 + srow) * K + scol;
    const size_t gb0 = (size_t)(col0 + srow) * K + scol;
    const size_t gb1 = (size_t)(col0 + 64 + srow) * K + scol;
    const int l0 = srow * 32 + scol;
    const int l1 = (64 + srow) * 32 + scol;

    f32x4 acc[4][4];
#pragma unroll
    for (int i = 0; i < 4; ++i)
#pragma unroll
        for (int j = 0; j < 4; ++j) acc[i][j] = (f32x4){0.f, 0.f, 0.f, 0.f};

    const int rfo = ((lane & 15) * 32) + ((lane >> 4) << 3);

    for (int kt = 0; kt < K; kt += 32) {
        __syncthreads();
        gll16(Ah + ga0 + kt, &lsAh[l0]);
        gll16(Ah + ga1 + kt, &lsAh[l1]);
        gll16(Al + ga0 + kt, &lsAl[l0]);
        gll16(Al + ga1 + kt, &lsAl[l1]);
        gll16(Wh + gb0 + kt, &lsBh[l0]);
        gll16(Wh + gb1 + kt, &lsBh[l1]);
        gll16(Wl + gb0 + kt, &lsBl[l0]);
        gll16(Wl + gb1 + kt, &lsBl[l1]);
        __syncthreads();
        bf16x8 afh[4], afl[4], bfh[4], bfl[4];
#pragma unroll
        for (int i = 0; i < 4; ++i) {
            afh[i] = *(const bf16x8*)&lsAh[(wm * 64 + i * 16) * 32 + rfo];
            afl[i] = *(const bf16x8*)&lsAl[(wm * 64 + i * 16) * 32 + rfo];
        }
#pragma unroll
        for (int j = 0; j < 4; ++j) {
            bfh[j] = *(const bf16x8*)&lsBh[(wn * 64 + j * 16) * 32 + rfo];
            bfl[j] = *(const bf16x8*)&lsBl[(wn * 64 + j * 16) * 32 + rfo];
        }
#pragma unroll
        for (int i = 0; i < 4; ++i)
#pragma unroll
            for (int j = 0; j < 4; ++j) {
                acc[i][j] = __builtin_amdgcn_mfma_f32_16x16x32_bf16(afh[i], bfh[j], acc[i][j], 0, 0, 0);
                acc[i][j] = __builtin_amdgcn_mfma_f32_16x16x32_bf16(afh[i], bfl[j], acc[i][j], 0, 0, 0);
                acc[i][j] = __builtin_amdgcn_mfma_f32_16x16x32_bf16(afl[i], bfh[j], acc[i][j], 0, 0, 0);
            }
    }

    const int rbase = row0 + wm * 64 + ((lane >> 4) << 2);
    const int cbase = col0 + wn * 64 + (lane & 15);
#pragma unroll
    for (int i = 0; i < 4; ++i) {
#pragma unroll
        for (int j = 0; j < 4; ++j) {
            const int cg = cbase + j * 16;
            float bv = (SMODE == 1) ? bias[cg] : 0.f;
#pragma unroll
            for (int q = 0; q < 4; ++q) {
                const int rg = rbase + i * 16 + q;
                const size_t off = (size_t)rg * N + cg;
                float v = acc[i][j][q];
                if (SMODE == 1) {
                    float x = v + bv;
                    Cout[off] = x * sigmoid_fast(x);
                } else {
                    Cout[off] = v;
                }
            }
        }
    }
}

// ---------------------------------------------------------------------------
// plain bf16 MFMA GEMM. MODE 0: fp32 out.  MODE 2: +resid*Dv, fp32 out.
// ---------------------------------------------------------------------------
template <int MODE>
__global__ __launch_bounds__(256) void mfma_gemm(
    const unsigned short* __restrict__ A, const unsigned short* __restrict__ W,
    float* __restrict__ Cout, int N,
    const float* __restrict__ resid, const float* __restrict__ Dv)
{
    constexpr int K = 768;
    __shared__ unsigned short lsA[128 * 32];
    __shared__ unsigned short lsB[128 * 32];
    const int tid  = threadIdx.x;
    const int wave = tid >> 6, lane = tid & 63;
    const int wm = wave >> 1, wn = wave & 1;
    const int row0 = blockIdx.x * 128, col0 = blockIdx.y * 128;

    const int srow = (wave << 4) + (lane >> 2);
    const int scol = (lane & 3) << 3;
    const size_t ga0 = (size_t)(row0 + srow) * K + scol;
    const size_t ga1 = (size_t)(row0 + 64 + srow) * K + scol;
    const size_t gb0 = (size_t)(col0 + srow) * K + scol;
    const size_t gb1 = (size_t)(col0 + 64 + srow) * K + scol;
    const int l0 = srow * 32 + scol;
    const int l1 = (64 + srow) * 32 + scol;

    f32x4 acc[4][4];
#pragma unroll
    for (int i = 0; i < 4; ++i)
#pragma unroll
        for (int j = 0; j < 4; ++j) acc[i][j] = (f32x4){0.f, 0.f, 0.f, 0.f};

    const int rfo = ((lane & 15) * 32) + ((lane >> 4) << 3);

    for (int kt = 0; kt < K; kt += 32) {
        __syncthreads();
        gll16(A + ga0 + kt, &lsA[l0]);
        gll16(A + ga1 + kt, &lsA[l1]);
        gll16(W + gb0 + kt, &lsB[l0]);
        gll16(W + gb1 + kt, &lsB[l1]);
        __syncthreads();
        bf16x8 af[4], bfg[4];
#pragma unroll
        for (int i = 0; i < 4; ++i)
            af[i] = *(const bf16x8*)&lsA[(wm * 64 + i * 16) * 32 + rfo];
#pragma unroll
        for (int j = 0; j < 4; ++j)
            bfg[j] = *(const bf16x8*)&lsB[(wn * 64 + j * 16) * 32 + rfo];
#pragma unroll
        for (int i = 0; i < 4; ++i)
#pragma unroll
            for (int j = 0; j < 4; ++j)
                acc[i][j] = __builtin_amdgcn_mfma_f32_16x16x32_bf16(af[i], bfg[j], acc[i][j], 0, 0, 0);
    }

    const int rbase = row0 + wm * 64 + ((lane >> 4) << 2);
    const int cbase = col0 + wn * 64 + (lane & 15);
#pragma unroll
    for (int i = 0; i < 4; ++i) {
#pragma unroll
        for (int j = 0; j < 4; ++j) {
            const int cg = cbase + j * 16;
            float dv = (MODE == 2) ? Dv[cg] : 0.f;
#pragma unroll
            for (int q = 0; q < 4; ++q) {
                const int rg = rbase + i * 16 + q;
                const size_t off = (size_t)rg * N + cg;
                float v = acc[i][j][q];
                if (MODE == 2) v += resid[off] * dv;
                Cout[off] = v;
            }
        }
    }
}

// ---------------------------------------------------------------------------
// Causal depthwise conv (K=4) + bias + silu. fp32 in, hi/lo bf16 out.
// ---------------------------------------------------------------------------
__global__ __launch_bounds__(256) void conv_silu_kernel(
    const float* __restrict__ x, const float* __restrict__ w,
    const float* __restrict__ cb, unsigned short* __restrict__ yh,
    unsigned short* __restrict__ yl)
{
    int idx = blockIdx.x * 256 + threadIdx.x;
    if (idx >= MM * HH) return;
    int h  = idx % HH;
    int ml = idx / HH;
    int l  = ml % LL;
    float acc = cb[h];
#pragma unroll
    for (int j = 0; j < KK; ++j) {
        int d = (KK - 1) - j;
        if (l - d >= 0) acc = fmaf(x[(size_t)(ml - d) * HH + h], w[h * KK + j], acc);
    }
    float y = acc * sigmoid_fast(acc);
    split_bf(y, yh[idx], yl[idx]);
}

// ---------------------------------------------------------------------------
// Chunked scan phases (fp32 state; states written bf16).
// ---------------------------------------------------------------------------
__global__ __launch_bounds__(256) void scan_chunk_kernel(
    const float* __restrict__ heads, const float* __restrict__ bu,
    const float* __restrict__ r_base, const float* __restrict__ th_base,
    const float* __restrict__ dt_base, const float* __restrict__ inj,
    float4* __restrict__ summA, float4* __restrict__ summB)
{
    int g = blockIdx.x * 256 + threadIdx.x;
    if (g >= NC * NCH) return;
    int t = g % NCH;
    int j = g / NCH;
    int b = t / PP, p = t - b * PP;
    const float rb = r_base[p], tb = th_base[p], il = inj[p];
    const float dt = 0.02f + 0.98f / (1.0f + expf(-dt_base[p]));
    float m00 = 1.f, m01 = 0.f, m10 = 0.f, m11 = 1.f;
    float vzR = 0.f, vxR = 0.f, vzI = 0.f, vxI = 0.f;
    const int mbase = b * LL + j * CLEN;
    for (int l = 0; l < CLEN; ++l) {
        const size_t m = (size_t)(mbase + l);
        const float Rp = heads[m * 1152 + p];
        const float Tp = heads[m * 1152 + 384 + p];
        const float Ip = heads[m * 1152 + 768 + p];
        const float b0 = bu[m * 768 + p];
        const float b1 = bu[m * 768 + 384 + p];
        float c0, c1, gdt;
        step_coef(Rp, Tp, Ip, rb, tb, il, dt, c0, c1, gdt);
        const float azR = gdt * b0, azI = gdt * b1;
        float nm00 = c0 * m00 - c1 * m10;
        float nm01 = c0 * m01 - c1 * m11;
        m10 = fmaf(dt, nm00, m10);
        m11 = fmaf(dt, nm01, m11);
        m00 = nm00; m01 = nm01;
        float nvzR = c0 * vzR - c1 * vxR + azR;
        vxR = fmaf(dt, nvzR, vxR); vzR = nvzR;
        float nvzI = c0 * vzI - c1 * vxI + azI;
        vxI = fmaf(dt, nvzI, vxI); vzI = nvzI;
    }
    summA[g] = make_float4(m00, m01, m10, m11);
    summB[g] = make_float4(vzR, vxR, vzI, vxI);
}

__global__ __launch_bounds__(256) void scan_mid_kernel(
    const float4* __restrict__ summA, const float4* __restrict__ summB,
    float4* __restrict__ starts)
{
    int t = blockIdx.x * 256 + threadIdx.x;
    if (t >= NCH) return;
    float zR = 0.f, xR = 0.f, zI = 0.f, xI = 0.f;
    for (int j = 0; j < NC; ++j) {
        starts[j * NCH + t] = make_float4(zR, xR, zI, xI);
        float4 Mv = summA[j * NCH + t];
        float4 Vv = summB[j * NCH + t];
        float nzR = Mv.x * zR + Mv.y * xR + Vv.x;
        float nxR = Mv.z * zR + Mv.w * xR + Vv.y;
        float nzI = Mv.x * zI + Mv.y * xI + Vv.z;
        float nxI = Mv.z * zI + Mv.w * xI + Vv.w;
        zR = nzR; xR = nxR; zI = nzI; xI = nxI;
    }
}

__global__ __launch_bounds__(256) void scan_apply_kernel(
    const float* __restrict__ heads, const float* __restrict__ bu,
    const float* __restrict__ r_base, const float* __restrict__ th_base,
    const float* __restrict__ dt_base, const float* __restrict__ inj,
    const float4* __restrict__ starts, unsigned short* __restrict__ states)
{
    int g = blockIdx.x * 256 + threadIdx.x;
    if (g >= NC * NCH) return;
    int t = g % NCH;
    int j = g / NCH;
    int b = t / PP, p = t - b * PP;
    const float rb = r_base[p], tb = th_base[p], il = inj[p];
    const float dt = 0.02f + 0.98f / (1.0f + expf(-dt_base[p]));
    float4 s0 = starts[j * NCH + t];
    float zR = s0.x, xR = s0.y, zI = s0.z, xI = s0.w;
    const int mbase = b * LL + j * CLEN;
    for (int l = 0; l < CLEN; ++l) {
        const size_t m = (size_t)(mbase + l);
        const float Rp = heads[m * 1152 + p];
        const float Tp = heads[m * 1152 + 384 + p];
        const float Ip = heads[m * 1152 + 768 + p];
        const float b0 = bu[m * 768 + p];
        const float b1 = bu[m * 768 + 384 + p];
        float c0, c1, gdt;
        step_coef(Rp, Tp, Ip, rb, tb, il, dt, c0, c1, gdt);
        zR = c0 * zR - c1 * xR + gdt * b0;
        xR = fmaf(dt, zR, xR);
        zI = c0 * zI - c1 * xI + gdt * b1;
        xI = fmaf(dt, zI, xI);
        states[m * 768 + p]       = f2bf(xR);
        states[m * 768 + 384 + p] = f2bf(xI);
    }
}

// ---------------------------------------------------------------------------
extern "C" void kernel_launch(void* const* d_in, const int* in_sizes, int n_in,
                              void* d_out, int out_size, void* d_ws, size_t ws_size,
                              hipStream_t stream)
{
    const float* inputs  = (const float*)d_in[0];
    const float* Wl      = (const float*)d_in[1];
    const float* bl      = (const float*)d_in[2];
    const float* conv_w  = (const float*)d_in[3];
    const float* conv_b  = (const float*)d_in[4];
    const float* Wr      = (const float*)d_in[5];
    const float* Wth     = (const float*)d_in[6];
    const float* Winj    = (const float*)d_in[7];
    const float* r_base  = (const float*)d_in[8];
    const float* th_base = (const float*)d_in[9];
    const float* dt_base = (const float*)d_in[10];
    const float* inj_l   = (const float*)d_in[11];
    const float* Bp      = (const float*)d_in[12];
    const float* Cp      = (const float*)d_in[13];
    const float* Dv      = (const float*)d_in[14];
    float* out = (float*)d_out;

    // ---- workspace layout (lifetime-aliased) ----
    const size_t NB = 768 * 768, NHd = 1152 * 768, NMH = (size_t)MM * 768;
    unsigned short* wlh = (unsigned short*)d_ws;
    unsigned short* wll = wlh + NB;
    unsigned short* whh = wll + NB;
    unsigned short* whl = whh + NHd;
    unsigned short* wb  = whl + NHd;
    unsigned short* wc  = wb + NB;
    unsigned short* inh = wc + NB;            // MM*768 bf16, live t2..t5
    unsigned short* inl = inh + NMH;          // MM*768 bf16, live t2 only
    unsigned short* f2h = inl + NMH;          // conv out hi, live t3..t4
    unsigned short* f2l = f2h + NMH;          // conv out lo
    float* f1    = (float*)(f2l + NMH);       // enc out fp32 (96MB), dead after t3
    float* heads = f1;                        // heads fp32 (144MB) overlays f1 (written t4)
    float4* summA = (float4*)((char*)heads + (size_t)MM * 1152 * 4);
    float4* summB = summA + (size_t)NC * NCH;
    float4* starts= summB + (size_t)NC * NCH;
    float* bu = (float*)d_out;                // fp32, written t5, dead after scan
    unsigned short* states = inl;             // bf16 MM*768, overlays dead inl

    // t1. repack weights + split-convert inputs
    {
        int total = (int)(NB + NHd + NB + NB);
        repack_kernel<<<(total + 255) / 256, 256, 0, stream>>>(
            Wl, Wr, Wth, Winj, Bp, Cp, wlh, wll, whh, whl, wb, wc);
        int n4 = (int)(NMH / 4);
        split_convert_kernel<<<(n4 + 255) / 256, 256, 0, stream>>>(inputs, inh, inl, n4);
    }
    // t2. encoder (split): f1 = silu(inputs @ Wl^T + bl)  [fp32]
    mfma_gemm_split<1><<<dim3(MM / 128, 768 / 128), 256, 0, stream>>>(
        inh, inl, wlh, wll, f1, 768, bl);
    // t3. conv + silu: f1 -> f2 hi/lo
    conv_silu_kernel<<<(MM * HH + 255) / 256, 256, 0, stream>>>(f1, conv_w, conv_b, f2h, f2l);
    // t4. heads (split): heads = f2 @ wh^T  [fp32]
    mfma_gemm_split<0><<<dim3(MM / 128, 1152 / 128), 256, 0, stream>>>(
        f2h, f2l, whh, whl, heads, 1152, nullptr);
    // t5. input projection (plain bf16): bu = inputs @ wb^T  [fp32, in d_out]
    mfma_gemm<0><<<dim3(MM / 128, 768 / 128), 256, 0, stream>>>(
        inh, wb, bu, 768, nullptr, nullptr);
    // t6. chunked scan
    scan_chunk_kernel<<<(NC * NCH) / 256, 256, 0, stream>>>(
        heads, bu, r_base, th_base, dt_base, inj_l, summA, summB);
    scan_mid_kernel<<<(NCH + 255) / 256, 256, 0, stream>>>(summA, summB, starts);
    scan_apply_kernel<<<(NC * NCH) / 256, 256, 0, stream>>>(
        heads, bu, r_base, th_base, dt_base, inj_l, starts, states);
    // t7. output projection + residual (plain bf16): out = states @ wc^T + inputs*D
    mfma_gemm<2><<<dim3(MM / 128, 768 / 128), 256, 0, stream>>>(
        states, wc, out, 768, inputs, Dv);
}

// Round 6
// 772.141 us; speedup vs baseline: 4.9015x; 1.0832x over previous
//
#include <hip/hip_runtime.h>
#include <math.h>

#define PP 384
#define HH 768
#define KK 4
#define BB 16
#define LL 2048
#define MM (BB*LL)   // 32768
#define NCH (BB*PP)  // 6144
#define NC 32
#define CLEN (LL/NC) // 64

typedef __attribute__((ext_vector_type(8))) short bf16x8;
typedef __attribute__((ext_vector_type(4))) float f32x4;

__device__ __forceinline__ float sigmoid_fast(float x) { return 1.0f / (1.0f + __expf(-x)); }

__device__ __forceinline__ float bf2f(unsigned short h) {
    return __uint_as_float(((unsigned int)h) << 16);
}
__device__ __forceinline__ unsigned short f2bf(float x) {
    unsigned int u = __float_as_uint(x);
    u += 0x7fff + ((u >> 16) & 1);          // round-to-nearest-even
    return (unsigned short)(u >> 16);
}
// split x into hi (bf16) and lo (bf16 of residual): x ≈ hi + lo, err ~2^-17
__device__ __forceinline__ void split_bf(float x, unsigned short& hi, unsigned short& lo) {
    hi = f2bf(x);
    lo = f2bf(x - bf2f(hi));
}

__device__ __forceinline__ void gll16(const void* g, void* l) {
    __builtin_amdgcn_global_load_lds(
        (const __attribute__((address_space(1))) void*)g,
        (__attribute__((address_space(3))) void*)l, 16, 0, 0);
}

// Per-step scalar coefficients (state-independent). Fast-math versions are
// used identically in compose and apply phases (internally consistent).
__device__ __forceinline__ void step_coef(float Rp, float Tp, float Ip,
    float rb, float tb, float il, float dt,
    float& c0, float& c1, float& gdt)
{
    const float PIf = 3.14159265358979323846f;
    float r  = sigmoid_fast(rb + Rp);
    float t  = tb + Tp;
    float e2 = __expf(2.0f * fabsf(t));
    float th = PIf * copysignf(1.0f - 2.0f / (e2 + 1.0f), t);
    float ct = __cosf(th);
    float r2 = fmaxf(r * r, 1e-8f);
    float Ac = (r2 - 2.0f * r * ct + 1.0f) / (dt * dt * r2);
    float Gc = (1.0f - r2) / (dt * r2);
    float S  = 1.0f / (1.0f + dt * Gc);
    float gate = sigmoid_fast(il + Ip);
    c0 = S;
    c1 = S * (dt * Ac);
    gdt = S * dt * gate;
}

// ---------------------------------------------------------------------------
// Weight repack:
//  wlh/wll (768x768)     = Wl split hi/lo
//  wrth h/l (768x768)    = [Wr;Wth] split hi/lo
//  winj (384x768) bf16   = Winj
//  wb (768x768) bf16     = [BRe;BIm]
//  wc (768x768) bf16     : cols [0,384)=CRe, [384,768)=-CIm
// ---------------------------------------------------------------------------
__global__ __launch_bounds__(256) void repack_kernel(
    const float* __restrict__ Wl, const float* __restrict__ Wr,
    const float* __restrict__ Wth, const float* __restrict__ Winj,
    const float* __restrict__ Bp, const float* __restrict__ Cp,
    unsigned short* __restrict__ wlh, unsigned short* __restrict__ wll,
    unsigned short* __restrict__ wrth_h, unsigned short* __restrict__ wrth_l,
    unsigned short* __restrict__ winj,
    unsigned short* __restrict__ wb, unsigned short* __restrict__ wc)
{
    int i = blockIdx.x * 256 + threadIdx.x;
    const int NB = 768 * 768, NI = 384 * 768;
    if (i < NB) { split_bf(Wl[i], wlh[i], wll[i]); return; }
    i -= NB;
    if (i < NB) {    // [Wr;Wth] rows 0..767
        int n = i / 768, k = i - n * 768;
        float v = (n < 384) ? Wr[n * 768 + k] : Wth[(n - 384) * 768 + k];
        split_bf(v, wrth_h[i], wrth_l[i]);
        return;
    }
    i -= NB;
    if (i < NI) { winj[i] = f2bf(Winj[i]); return; }
    i -= NI;
    if (i < NB) {
        int n = i / 768, k = i - n * 768;
        wb[i] = f2bf((n < 384) ? Bp[n * 1536 + k * 2] : Bp[(n - 384) * 1536 + k * 2 + 1]);
        return;
    }
    i -= NB;
    if (i < NB) {
        int n = i / 768, k = i - n * 768;
        wc[i] = f2bf((k < 384) ? Cp[n * 768 + k * 2] : -Cp[n * 768 + (k - 384) * 2 + 1]);
    }
}

// inputs -> hi/lo split buffers
__global__ __launch_bounds__(256) void split_convert_kernel(
    const float* __restrict__ in, unsigned short* __restrict__ outh,
    unsigned short* __restrict__ outl, int n4)
{
    int i = blockIdx.x * 256 + threadIdx.x;
    if (i >= n4) return;
    float4 a = ((const float4*)in)[i];
    ushort4 h, l;
    split_bf(a.x, h.x, l.x); split_bf(a.y, h.y, l.y);
    split_bf(a.z, h.z, l.z); split_bf(a.w, h.w, l.w);
    ((ushort4*)outh)[i] = h;
    ((ushort4*)outl)[i] = l;
}

// ---------------------------------------------------------------------------
// SPLIT-PRECISION bf16 MFMA GEMM: C = (Ah+Al) @ (Wh+Wl)^T  (3 MFMAs/k-step)
// grid = (N/128, M/128)  [col-fast for A-panel/W L2 reuse]
// SMODE 0: fp32 out. SMODE 1: +bias, silu, fp32 out.
// ---------------------------------------------------------------------------
template <int SMODE>
__global__ __launch_bounds__(256) void mfma_gemm_split(
    const unsigned short* __restrict__ Ah, const unsigned short* __restrict__ Al,
    const unsigned short* __restrict__ Wh, const unsigned short* __restrict__ Wl,
    float* __restrict__ Cout, int N, const float* __restrict__ bias)
{
    constexpr int K = 768;
    __shared__ unsigned short lsAh[128 * 32];
    __shared__ unsigned short lsAl[128 * 32];
    __shared__ unsigned short lsBh[128 * 32];
    __shared__ unsigned short lsBl[128 * 32];
    const int tid  = threadIdx.x;
    const int wave = tid >> 6, lane = tid & 63;
    const int wm = wave >> 1, wn = wave & 1;
    const int row0 = blockIdx.y * 128, col0 = blockIdx.x * 128;

    const int srow = (wave << 4) + (lane >> 2);    // 0..63
    const int scol = (lane & 3) << 3;              // 0,8,16,24
    const size_t ga0 = (size_t)(row0 + srow) * K + scol;
    const size_t ga1 = (size_t)(row0 + 64 + srow) * K + scol;
    const size_t gb0 = (size_t)(col0 + srow) * K + scol;
    const size_t gb1 = (size_t)(col0 + 64 + srow) * K + scol;
    const int l0 = srow * 32 + scol;
    const int l1 = (64 + srow) * 32 + scol;

    f32x4 acc[4][4];
#pragma unroll
    for (int i = 0; i < 4; ++i)
#pragma unroll
        for (int j = 0; j < 4; ++j) acc[i][j] = (f32x4){0.f, 0.f, 0.f, 0.f};

    const int rfo = ((lane & 15) * 32) + ((lane >> 4) << 3);

    for (int kt = 0; kt < K; kt += 32) {
        __syncthreads();
        gll16(Ah + ga0 + kt, &lsAh[l0]);
        gll16(Ah + ga1 + kt, &lsAh[l1]);
        gll16(Al + ga0 + kt, &lsAl[l0]);
        gll16(Al + ga1 + kt, &lsAl[l1]);
        gll16(Wh + gb0 + kt, &lsBh[l0]);
        gll16(Wh + gb1 + kt, &lsBh[l1]);
        gll16(Wl + gb0 + kt, &lsBl[l0]);
        gll16(Wl + gb1 + kt, &lsBl[l1]);
        __syncthreads();
        bf16x8 afh[4], afl[4], bfh[4], bfl[4];
#pragma unroll
        for (int i = 0; i < 4; ++i) {
            afh[i] = *(const bf16x8*)&lsAh[(wm * 64 + i * 16) * 32 + rfo];
            afl[i] = *(const bf16x8*)&lsAl[(wm * 64 + i * 16) * 32 + rfo];
        }
#pragma unroll
        for (int j = 0; j < 4; ++j) {
            bfh[j] = *(const bf16x8*)&lsBh[(wn * 64 + j * 16) * 32 + rfo];
            bfl[j] = *(const bf16x8*)&lsBl[(wn * 64 + j * 16) * 32 + rfo];
        }
#pragma unroll
        for (int i = 0; i < 4; ++i)
#pragma unroll
            for (int j = 0; j < 4; ++j) {
                acc[i][j] = __builtin_amdgcn_mfma_f32_16x16x32_bf16(afh[i], bfh[j], acc[i][j], 0, 0, 0);
                acc[i][j] = __builtin_amdgcn_mfma_f32_16x16x32_bf16(afh[i], bfl[j], acc[i][j], 0, 0, 0);
                acc[i][j] = __builtin_amdgcn_mfma_f32_16x16x32_bf16(afl[i], bfh[j], acc[i][j], 0, 0, 0);
            }
    }

    const int rbase = row0 + wm * 64 + ((lane >> 4) << 2);
    const int cbase = col0 + wn * 64 + (lane & 15);
#pragma unroll
    for (int i = 0; i < 4; ++i) {
#pragma unroll
        for (int j = 0; j < 4; ++j) {
            const int cg = cbase + j * 16;
            float bv = (SMODE == 1) ? bias[cg] : 0.f;
#pragma unroll
            for (int q = 0; q < 4; ++q) {
                const int rg = rbase + i * 16 + q;
                const size_t off = (size_t)rg * N + cg;
                float v = acc[i][j][q];
                if (SMODE == 1) {
                    float x = v + bv;
                    Cout[off] = x * sigmoid_fast(x);
                } else {
                    Cout[off] = v;
                }
            }
        }
    }
}

// ---------------------------------------------------------------------------
// plain bf16 MFMA GEMM. grid = (N/128, M/128).
// MODE 2: +resid*Dv, fp32 out.  MODE 3: bf16 out, no epilogue.
// ---------------------------------------------------------------------------
template <int MODE>
__global__ __launch_bounds__(256) void mfma_gemm(
    const unsigned short* __restrict__ A, const unsigned short* __restrict__ W,
    void* __restrict__ Cout, int N,
    const float* __restrict__ resid, const float* __restrict__ Dv)
{
    constexpr int K = 768;
    __shared__ unsigned short lsA[128 * 32];
    __shared__ unsigned short lsB[128 * 32];
    const int tid  = threadIdx.x;
    const int wave = tid >> 6, lane = tid & 63;
    const int wm = wave >> 1, wn = wave & 1;
    const int row0 = blockIdx.y * 128, col0 = blockIdx.x * 128;

    const int srow = (wave << 4) + (lane >> 2);
    const int scol = (lane & 3) << 3;
    const size_t ga0 = (size_t)(row0 + srow) * K + scol;
    const size_t ga1 = (size_t)(row0 + 64 + srow) * K + scol;
    const size_t gb0 = (size_t)(col0 + srow) * K + scol;
    const size_t gb1 = (size_t)(col0 + 64 + srow) * K + scol;
    const int l0 = srow * 32 + scol;
    const int l1 = (64 + srow) * 32 + scol;

    f32x4 acc[4][4];
#pragma unroll
    for (int i = 0; i < 4; ++i)
#pragma unroll
        for (int j = 0; j < 4; ++j) acc[i][j] = (f32x4){0.f, 0.f, 0.f, 0.f};

    const int rfo = ((lane & 15) * 32) + ((lane >> 4) << 3);

    for (int kt = 0; kt < K; kt += 32) {
        __syncthreads();
        gll16(A + ga0 + kt, &lsA[l0]);
        gll16(A + ga1 + kt, &lsA[l1]);
        gll16(W + gb0 + kt, &lsB[l0]);
        gll16(W + gb1 + kt, &lsB[l1]);
        __syncthreads();
        bf16x8 af[4], bfg[4];
#pragma unroll
        for (int i = 0; i < 4; ++i)
            af[i] = *(const bf16x8*)&lsA[(wm * 64 + i * 16) * 32 + rfo];
#pragma unroll
        for (int j = 0; j < 4; ++j)
            bfg[j] = *(const bf16x8*)&lsB[(wn * 64 + j * 16) * 32 + rfo];
#pragma unroll
        for (int i = 0; i < 4; ++i)
#pragma unroll
            for (int j = 0; j < 4; ++j)
                acc[i][j] = __builtin_amdgcn_mfma_f32_16x16x32_bf16(af[i], bfg[j], acc[i][j], 0, 0, 0);
    }

    const int rbase = row0 + wm * 64 + ((lane >> 4) << 2);
    const int cbase = col0 + wn * 64 + (lane & 15);
#pragma unroll
    for (int i = 0; i < 4; ++i) {
#pragma unroll
        for (int j = 0; j < 4; ++j) {
            const int cg = cbase + j * 16;
            float dv = (MODE == 2) ? Dv[cg] : 0.f;
#pragma unroll
            for (int q = 0; q < 4; ++q) {
                const int rg = rbase + i * 16 + q;
                const size_t off = (size_t)rg * N + cg;
                float v = acc[i][j][q];
                if (MODE == 2) {
                    ((float*)Cout)[off] = v + resid[off] * dv;
                } else {
                    ((unsigned short*)Cout)[off] = f2bf(v);
                }
            }
        }
    }
}

// ---------------------------------------------------------------------------
// Causal depthwise conv (K=4) + bias + silu. fp32 in, hi/lo bf16 out.
// ---------------------------------------------------------------------------
__global__ __launch_bounds__(256) void conv_silu_kernel(
    const float* __restrict__ x, const float* __restrict__ w,
    const float* __restrict__ cb, unsigned short* __restrict__ yh,
    unsigned short* __restrict__ yl)
{
    int idx = blockIdx.x * 256 + threadIdx.x;
    if (idx >= MM * HH) return;
    int h  = idx % HH;
    int ml = idx / HH;
    int l  = ml % LL;
    float acc = cb[h];
#pragma unroll
    for (int j = 0; j < KK; ++j) {
        int d = (KK - 1) - j;
        if (l - d >= 0) acc = fmaf(x[(size_t)(ml - d) * HH + h], w[h * KK + j], acc);
    }
    float y = acc * sigmoid_fast(acc);
    split_bf(y, yh[idx], yl[idx]);
}

// ---------------------------------------------------------------------------
// Chunked scan. heads_rt (M,768) fp32: [Rpre|Thpre]. heads_inj (M,384) bf16.
// bu (M,768) bf16: [Re|Im]. states (M,768) bf16 out.
// ---------------------------------------------------------------------------
__global__ __launch_bounds__(256) void scan_chunk_kernel(
    const float* __restrict__ heads_rt, const unsigned short* __restrict__ heads_inj,
    const unsigned short* __restrict__ bu,
    const float* __restrict__ r_base, const float* __restrict__ th_base,
    const float* __restrict__ dt_base, const float* __restrict__ inj,
    float4* __restrict__ summA, float4* __restrict__ summB)
{
    int g = blockIdx.x * 256 + threadIdx.x;
    if (g >= NC * NCH) return;
    int t = g % NCH;
    int j = g / NCH;
    int b = t / PP, p = t - b * PP;
    const float rb = r_base[p], tb = th_base[p], il = inj[p];
    const float dt = 0.02f + 0.98f * sigmoid_fast(dt_base[p]);
    float m00 = 1.f, m01 = 0.f, m10 = 0.f, m11 = 1.f;
    float vzR = 0.f, vxR = 0.f, vzI = 0.f, vxI = 0.f;
    const int mbase = b * LL + j * CLEN;
    for (int l = 0; l < CLEN; ++l) {
        const size_t m = (size_t)(mbase + l);
        const float Rp = heads_rt[m * 768 + p];
        const float Tp = heads_rt[m * 768 + 384 + p];
        const float Ip = bf2f(heads_inj[m * 384 + p]);
        const float b0 = bf2f(bu[m * 768 + p]);
        const float b1 = bf2f(bu[m * 768 + 384 + p]);
        float c0, c1, gdt;
        step_coef(Rp, Tp, Ip, rb, tb, il, dt, c0, c1, gdt);
        const float azR = gdt * b0, azI = gdt * b1;
        float nm00 = c0 * m00 - c1 * m10;
        float nm01 = c0 * m01 - c1 * m11;
        m10 = fmaf(dt, nm00, m10);
        m11 = fmaf(dt, nm01, m11);
        m00 = nm00; m01 = nm01;
        float nvzR = c0 * vzR - c1 * vxR + azR;
        vxR = fmaf(dt, nvzR, vxR); vzR = nvzR;
        float nvzI = c0 * vzI - c1 * vxI + azI;
        vxI = fmaf(dt, nvzI, vxI); vzI = nvzI;
    }
    summA[g] = make_float4(m00, m01, m10, m11);
    summB[g] = make_float4(vzR, vxR, vzI, vxI);
}

__global__ __launch_bounds__(256) void scan_mid_kernel(
    const float4* __restrict__ summA, const float4* __restrict__ summB,
    float4* __restrict__ starts)
{
    int t = blockIdx.x * 256 + threadIdx.x;
    if (t >= NCH) return;
    float zR = 0.f, xR = 0.f, zI = 0.f, xI = 0.f;
    for (int j = 0; j < NC; ++j) {
        starts[j * NCH + t] = make_float4(zR, xR, zI, xI);
        float4 Mv = summA[j * NCH + t];
        float4 Vv = summB[j * NCH + t];
        float nzR = Mv.x * zR + Mv.y * xR + Vv.x;
        float nxR = Mv.z * zR + Mv.w * xR + Vv.y;
        float nzI = Mv.x * zI + Mv.y * xI + Vv.z;
        float nxI = Mv.z * zI + Mv.w * xI + Vv.w;
        zR = nzR; xR = nxR; zI = nzI; xI = nxI;
    }
}

__global__ __launch_bounds__(256) void scan_apply_kernel(
    const float* __restrict__ heads_rt, const unsigned short* __restrict__ heads_inj,
    const unsigned short* __restrict__ bu,
    const float* __restrict__ r_base, const float* __restrict__ th_base,
    const float* __restrict__ dt_base, const float* __restrict__ inj,
    const float4* __restrict__ starts, unsigned short* __restrict__ states)
{
    int g = blockIdx.x * 256 + threadIdx.x;
    if (g >= NC * NCH) return;
    int t = g % NCH;
    int j = g / NCH;
    int b = t / PP, p = t - b * PP;
    const float rb = r_base[p], tb = th_base[p], il = inj[p];
    const float dt = 0.02f + 0.98f * sigmoid_fast(dt_base[p]);
    float4 s0 = starts[j * NCH + t];
    float zR = s0.x, xR = s0.y, zI = s0.z, xI = s0.w;
    const int mbase = b * LL + j * CLEN;
    for (int l = 0; l < CLEN; ++l) {
        const size_t m = (size_t)(mbase + l);
        const float Rp = heads_rt[m * 768 + p];
        const float Tp = heads_rt[m * 768 + 384 + p];
        const float Ip = bf2f(heads_inj[m * 384 + p]);
        const float b0 = bf2f(bu[m * 768 + p]);
        const float b1 = bf2f(bu[m * 768 + 384 + p]);
        float c0, c1, gdt;
        step_coef(Rp, Tp, Ip, rb, tb, il, dt, c0, c1, gdt);
        zR = c0 * zR - c1 * xR + gdt * b0;
        xR = fmaf(dt, zR, xR);
        zI = c0 * zI - c1 * xI + gdt * b1;
        xI = fmaf(dt, zI, xI);
        states[m * 768 + p]       = f2bf(xR);
        states[m * 768 + 384 + p] = f2bf(xI);
    }
}

// ---------------------------------------------------------------------------
extern "C" void kernel_launch(void* const* d_in, const int* in_sizes, int n_in,
                              void* d_out, int out_size, void* d_ws, size_t ws_size,
                              hipStream_t stream)
{
    const float* inputs  = (const float*)d_in[0];
    const float* Wl      = (const float*)d_in[1];
    const float* bl      = (const float*)d_in[2];
    const float* conv_w  = (const float*)d_in[3];
    const float* conv_b  = (const float*)d_in[4];
    const float* Wr      = (const float*)d_in[5];
    const float* Wth     = (const float*)d_in[6];
    const float* Winj    = (const float*)d_in[7];
    const float* r_base  = (const float*)d_in[8];
    const float* th_base = (const float*)d_in[9];
    const float* dt_base = (const float*)d_in[10];
    const float* inj_l   = (const float*)d_in[11];
    const float* Bp      = (const float*)d_in[12];
    const float* Cp      = (const float*)d_in[13];
    const float* Dv      = (const float*)d_in[14];
    float* out = (float*)d_out;

    // ---- workspace layout (lifetime-aliased) ----
    const size_t NB = 768 * 768, NI = 384 * 768, NMH = (size_t)MM * 768;
    unsigned short* wlh    = (unsigned short*)d_ws;
    unsigned short* wll    = wlh + NB;
    unsigned short* wrth_h = wll + NB;
    unsigned short* wrth_l = wrth_h + NB;
    unsigned short* winj   = wrth_l + NB;
    unsigned short* wb     = winj + NI;
    unsigned short* wc     = wb + NB;
    unsigned short* inh    = wc + NB;            // MM*768 bf16, live t2..t5
    unsigned short* inl    = inh + NMH;          // live t2 only -> states later
    unsigned short* f2h    = inl + NMH;          // conv out hi, live t3..t4b
    unsigned short* f2l    = f2h + NMH;          // conv out lo
    unsigned short* hinj   = f2l + NMH;          // heads_inj bf16 MM*384
    float* f1       = (float*)(hinj + (size_t)MM * 384);   // enc out fp32 (96MB)
    float* heads_rt = f1;                        // overlays f1 (dead after conv)
    float4* summA = (float4*)(f1 + NMH);
    float4* summB = summA + (size_t)NC * NCH;
    float4* starts= summB + (size_t)NC * NCH;
    unsigned short* bu = (unsigned short*)d_out; // bf16 MM*768, dead after scan
    unsigned short* states = inl;                // overlays dead inl

    // t1. repack weights + split-convert inputs
    {
        int total = (int)(4 * NB + NI);
        repack_kernel<<<(total + 255) / 256, 256, 0, stream>>>(
            Wl, Wr, Wth, Winj, Bp, Cp, wlh, wll, wrth_h, wrth_l, winj, wb, wc);
        int n4 = (int)(NMH / 4);
        split_convert_kernel<<<(n4 + 255) / 256, 256, 0, stream>>>(inputs, inh, inl, n4);
    }
    // t2. encoder (split): f1 = silu(inputs @ Wl^T + bl)  [fp32]
    mfma_gemm_split<1><<<dim3(768 / 128, MM / 128), 256, 0, stream>>>(
        inh, inl, wlh, wll, f1, 768, bl);
    // t3. conv + silu: f1 -> f2 hi/lo
    conv_silu_kernel<<<(MM * HH + 255) / 256, 256, 0, stream>>>(f1, conv_w, conv_b, f2h, f2l);
    // t4a. R/Th heads (split): heads_rt = f2 @ [Wr;Wth]^T  [fp32, overlays f1]
    mfma_gemm_split<0><<<dim3(768 / 128, MM / 128), 256, 0, stream>>>(
        f2h, f2l, wrth_h, wrth_l, heads_rt, 768, nullptr);
    // t4b. Inj head (plain): hinj = f2h @ Winj^T  [bf16]
    mfma_gemm<3><<<dim3(384 / 128, MM / 128), 256, 0, stream>>>(
        f2h, winj, (void*)hinj, 384, nullptr, nullptr);
    // t5. input projection (plain): bu = inputs @ wb^T  [bf16, in d_out]
    mfma_gemm<3><<<dim3(768 / 128, MM / 128), 256, 0, stream>>>(
        inh, wb, (void*)bu, 768, nullptr, nullptr);
    // t6. chunked scan
    scan_chunk_kernel<<<(NC * NCH) / 256, 256, 0, stream>>>(
        heads_rt, hinj, bu, r_base, th_base, dt_base, inj_l, summA, summB);
    scan_mid_kernel<<<(NCH + 255) / 256, 256, 0, stream>>>(summA, summB, starts);
    scan_apply_kernel<<<(NC * NCH) / 256, 256, 0, stream>>>(
        heads_rt, hinj, bu, r_base, th_base, dt_base, inj_l, starts, states);
    // t7. output projection + residual: out = states @ wc^T + inputs*D  [fp32]
    mfma_gemm<2><<<dim3(768 / 128, MM / 128), 256, 0, stream>>>(
        states, wc, (void*)out, 768, inputs, Dv);
}

// Round 7
// 719.964 us; speedup vs baseline: 5.2567x; 1.0725x over previous
//
#include <hip/hip_runtime.h>
#include <math.h>

#define PP 384
#define HH 768
#define KK 4
#define BB 16
#define LL 2048
#define MM (BB*LL)   // 32768
#define NCH (BB*PP)  // 6144
#define NC 32
#define CLEN (LL/NC) // 64

typedef __attribute__((ext_vector_type(8))) short bf16x8;
typedef __attribute__((ext_vector_type(4))) float f32x4;

__device__ __forceinline__ float sigmoid_fast(float x) { return 1.0f / (1.0f + __expf(-x)); }

__device__ __forceinline__ float bf2f(unsigned short h) {
    return __uint_as_float(((unsigned int)h) << 16);
}
__device__ __forceinline__ unsigned short f2bf(float x) {
    unsigned int u = __float_as_uint(x);
    u += 0x7fff + ((u >> 16) & 1);          // round-to-nearest-even
    return (unsigned short)(u >> 16);
}
// split x into hi (bf16) and lo (bf16 of residual): x ≈ hi + lo, err ~2^-17
__device__ __forceinline__ void split_bf(float x, unsigned short& hi, unsigned short& lo) {
    hi = f2bf(x);
    lo = f2bf(x - bf2f(hi));
}

__device__ __forceinline__ void gll16(const void* g, void* l) {
    __builtin_amdgcn_global_load_lds(
        (const __attribute__((address_space(1))) void*)g,
        (__attribute__((address_space(3))) void*)l, 16, 0, 0);
}

// Bijective XCD-aware block swizzle (m204): blocks resident on one XCD get
// CONSECUTIVE work units -> A row-panels fetched once chip-wide, W stays in
// per-XCD L2. Works for any nwg (bijective also when nwg % 8 != 0).
__device__ __forceinline__ void xcd_swizzle(int& bx, int& by) {
    const int gx = (int)gridDim.x;
    const int nwg = gx * (int)gridDim.y;
    const int orig = by * gx + bx;
    const int q = nwg >> 3, r = nwg & 7;
    const int xcd = orig & 7, off = orig >> 3;
    const int swz = (xcd < r ? xcd * (q + 1) : r * (q + 1) + (xcd - r) * q) + off;
    bx = swz % gx;
    by = swz / gx;
}

// Per-step scalar coefficients (state-independent). Fast-math versions are
// used identically in compose and apply phases (internally consistent).
__device__ __forceinline__ void step_coef(float Rp, float Tp, float Ip,
    float rb, float tb, float il, float dt,
    float& c0, float& c1, float& gdt)
{
    const float PIf = 3.14159265358979323846f;
    float r  = sigmoid_fast(rb + Rp);
    float t  = tb + Tp;
    float e2 = __expf(2.0f * fabsf(t));
    float th = PIf * copysignf(1.0f - 2.0f / (e2 + 1.0f), t);
    float ct = __cosf(th);
    float r2 = fmaxf(r * r, 1e-8f);
    float Ac = (r2 - 2.0f * r * ct + 1.0f) / (dt * dt * r2);
    float Gc = (1.0f - r2) / (dt * r2);
    float S  = 1.0f / (1.0f + dt * Gc);
    float gate = sigmoid_fast(il + Ip);
    c0 = S;
    c1 = S * (dt * Ac);
    gdt = S * dt * gate;
}

// ---------------------------------------------------------------------------
// Weight repack:
//  wlh/wll (768x768)     = Wl split hi/lo
//  wrth h/l (768x768)    = [Wr;Wth] split hi/lo
//  winj (384x768) bf16   = Winj
//  wb (768x768) bf16     = [BRe;BIm]
//  wc (768x768) bf16     : cols [0,384)=CRe, [384,768)=-CIm
// ---------------------------------------------------------------------------
__global__ __launch_bounds__(256) void repack_kernel(
    const float* __restrict__ Wl, const float* __restrict__ Wr,
    const float* __restrict__ Wth, const float* __restrict__ Winj,
    const float* __restrict__ Bp, const float* __restrict__ Cp,
    unsigned short* __restrict__ wlh, unsigned short* __restrict__ wll,
    unsigned short* __restrict__ wrth_h, unsigned short* __restrict__ wrth_l,
    unsigned short* __restrict__ winj,
    unsigned short* __restrict__ wb, unsigned short* __restrict__ wc)
{
    int i = blockIdx.x * 256 + threadIdx.x;
    const int NB = 768 * 768, NI = 384 * 768;
    if (i < NB) { split_bf(Wl[i], wlh[i], wll[i]); return; }
    i -= NB;
    if (i < NB) {    // [Wr;Wth] rows 0..767
        int n = i / 768, k = i - n * 768;
        float v = (n < 384) ? Wr[n * 768 + k] : Wth[(n - 384) * 768 + k];
        split_bf(v, wrth_h[i], wrth_l[i]);
        return;
    }
    i -= NB;
    if (i < NI) { winj[i] = f2bf(Winj[i]); return; }
    i -= NI;
    if (i < NB) {
        int n = i / 768, k = i - n * 768;
        wb[i] = f2bf((n < 384) ? Bp[n * 1536 + k * 2] : Bp[(n - 384) * 1536 + k * 2 + 1]);
        return;
    }
    i -= NB;
    if (i < NB) {
        int n = i / 768, k = i - n * 768;
        wc[i] = f2bf((k < 384) ? Cp[n * 768 + k * 2] : -Cp[n * 768 + (k - 384) * 2 + 1]);
    }
}

// inputs -> hi/lo split buffers
__global__ __launch_bounds__(256) void split_convert_kernel(
    const float* __restrict__ in, unsigned short* __restrict__ outh,
    unsigned short* __restrict__ outl, int n4)
{
    int i = blockIdx.x * 256 + threadIdx.x;
    if (i >= n4) return;
    float4 a = ((const float4*)in)[i];
    ushort4 h, l;
    split_bf(a.x, h.x, l.x); split_bf(a.y, h.y, l.y);
    split_bf(a.z, h.z, l.z); split_bf(a.w, h.w, l.w);
    ((ushort4*)outh)[i] = h;
    ((ushort4*)outl)[i] = l;
}

// ---------------------------------------------------------------------------
// SPLIT-PRECISION bf16 MFMA GEMM: C = (Ah+Al) @ (Wh+Wl)^T  (3 MFMAs/k-step)
// grid = (N/128, M/128), XCD-swizzled.
// SMODE 0: fp32 out. SMODE 1: +bias, silu, fp32 out.
// ---------------------------------------------------------------------------
template <int SMODE>
__global__ __launch_bounds__(256) void mfma_gemm_split(
    const unsigned short* __restrict__ Ah, const unsigned short* __restrict__ Al,
    const unsigned short* __restrict__ Wh, const unsigned short* __restrict__ Wl,
    float* __restrict__ Cout, int N, const float* __restrict__ bias)
{
    constexpr int K = 768;
    __shared__ unsigned short lsAh[128 * 32];
    __shared__ unsigned short lsAl[128 * 32];
    __shared__ unsigned short lsBh[128 * 32];
    __shared__ unsigned short lsBl[128 * 32];
    const int tid  = threadIdx.x;
    const int wave = tid >> 6, lane = tid & 63;
    const int wm = wave >> 1, wn = wave & 1;
    int bx = blockIdx.x, by = blockIdx.y;
    xcd_swizzle(bx, by);
    const int row0 = by * 128, col0 = bx * 128;

    const int srow = (wave << 4) + (lane >> 2);    // 0..63
    const int scol = (lane & 3) << 3;              // 0,8,16,24
    const size_t ga0 = (size_t)(row0 + srow) * K + scol;
    const size_t ga1 = (size_t)(row0 + 64 + srow) * K + scol;
    const size_t gb0 = (size_t)(col0 + srow) * K + scol;
    const size_t gb1 = (size_t)(col0 + 64 + srow) * K + scol;
    const int l0 = srow * 32 + scol;
    const int l1 = (64 + srow) * 32 + scol;

    f32x4 acc[4][4];
#pragma unroll
    for (int i = 0; i < 4; ++i)
#pragma unroll
        for (int j = 0; j < 4; ++j) acc[i][j] = (f32x4){0.f, 0.f, 0.f, 0.f};

    const int rfo = ((lane & 15) * 32) + ((lane >> 4) << 3);

    for (int kt = 0; kt < K; kt += 32) {
        __syncthreads();
        gll16(Ah + ga0 + kt, &lsAh[l0]);
        gll16(Ah + ga1 + kt, &lsAh[l1]);
        gll16(Al + ga0 + kt, &lsAl[l0]);
        gll16(Al + ga1 + kt, &lsAl[l1]);
        gll16(Wh + gb0 + kt, &lsBh[l0]);
        gll16(Wh + gb1 + kt, &lsBh[l1]);
        gll16(Wl + gb0 + kt, &lsBl[l0]);
        gll16(Wl + gb1 + kt, &lsBl[l1]);
        __syncthreads();
        bf16x8 afh[4], afl[4], bfh[4], bfl[4];
#pragma unroll
        for (int i = 0; i < 4; ++i) {
            afh[i] = *(const bf16x8*)&lsAh[(wm * 64 + i * 16) * 32 + rfo];
            afl[i] = *(const bf16x8*)&lsAl[(wm * 64 + i * 16) * 32 + rfo];
        }
#pragma unroll
        for (int j = 0; j < 4; ++j) {
            bfh[j] = *(const bf16x8*)&lsBh[(wn * 64 + j * 16) * 32 + rfo];
            bfl[j] = *(const bf16x8*)&lsBl[(wn * 64 + j * 16) * 32 + rfo];
        }
#pragma unroll
        for (int i = 0; i < 4; ++i)
#pragma unroll
            for (int j = 0; j < 4; ++j) {
                acc[i][j] = __builtin_amdgcn_mfma_f32_16x16x32_bf16(afh[i], bfh[j], acc[i][j], 0, 0, 0);
                acc[i][j] = __builtin_amdgcn_mfma_f32_16x16x32_bf16(afh[i], bfl[j], acc[i][j], 0, 0, 0);
                acc[i][j] = __builtin_amdgcn_mfma_f32_16x16x32_bf16(afl[i], bfh[j], acc[i][j], 0, 0, 0);
            }
    }

    const int rbase = row0 + wm * 64 + ((lane >> 4) << 2);
    const int cbase = col0 + wn * 64 + (lane & 15);
#pragma unroll
    for (int i = 0; i < 4; ++i) {
#pragma unroll
        for (int j = 0; j < 4; ++j) {
            const int cg = cbase + j * 16;
            float bv = (SMODE == 1) ? bias[cg] : 0.f;
#pragma unroll
            for (int q = 0; q < 4; ++q) {
                const int rg = rbase + i * 16 + q;
                const size_t off = (size_t)rg * N + cg;
                float v = acc[i][j][q];
                if (SMODE == 1) {
                    float x = v + bv;
                    Cout[off] = x * sigmoid_fast(x);
                } else {
                    Cout[off] = v;
                }
            }
        }
    }
}

// ---------------------------------------------------------------------------
// plain bf16 MFMA GEMM. grid = (N/128, M/128), XCD-swizzled.
// MODE 2: +resid*Dv, fp32 out.  MODE 3: bf16 out, no epilogue.
// ---------------------------------------------------------------------------
template <int MODE>
__global__ __launch_bounds__(256) void mfma_gemm(
    const unsigned short* __restrict__ A, const unsigned short* __restrict__ W,
    void* __restrict__ Cout, int N,
    const float* __restrict__ resid, const float* __restrict__ Dv)
{
    constexpr int K = 768;
    __shared__ unsigned short lsA[128 * 32];
    __shared__ unsigned short lsB[128 * 32];
    const int tid  = threadIdx.x;
    const int wave = tid >> 6, lane = tid & 63;
    const int wm = wave >> 1, wn = wave & 1;
    int bx = blockIdx.x, by = blockIdx.y;
    xcd_swizzle(bx, by);
    const int row0 = by * 128, col0 = bx * 128;

    const int srow = (wave << 4) + (lane >> 2);
    const int scol = (lane & 3) << 3;
    const size_t ga0 = (size_t)(row0 + srow) * K + scol;
    const size_t ga1 = (size_t)(row0 + 64 + srow) * K + scol;
    const size_t gb0 = (size_t)(col0 + srow) * K + scol;
    const size_t gb1 = (size_t)(col0 + 64 + srow) * K + scol;
    const int l0 = srow * 32 + scol;
    const int l1 = (64 + srow) * 32 + scol;

    f32x4 acc[4][4];
#pragma unroll
    for (int i = 0; i < 4; ++i)
#pragma unroll
        for (int j = 0; j < 4; ++j) acc[i][j] = (f32x4){0.f, 0.f, 0.f, 0.f};

    const int rfo = ((lane & 15) * 32) + ((lane >> 4) << 3);

    for (int kt = 0; kt < K; kt += 32) {
        __syncthreads();
        gll16(A + ga0 + kt, &lsA[l0]);
        gll16(A + ga1 + kt, &lsA[l1]);
        gll16(W + gb0 + kt, &lsB[l0]);
        gll16(W + gb1 + kt, &lsB[l1]);
        __syncthreads();
        bf16x8 af[4], bfg[4];
#pragma unroll
        for (int i = 0; i < 4; ++i)
            af[i] = *(const bf16x8*)&lsA[(wm * 64 + i * 16) * 32 + rfo];
#pragma unroll
        for (int j = 0; j < 4; ++j)
            bfg[j] = *(const bf16x8*)&lsB[(wn * 64 + j * 16) * 32 + rfo];
#pragma unroll
        for (int i = 0; i < 4; ++i)
#pragma unroll
            for (int j = 0; j < 4; ++j)
                acc[i][j] = __builtin_amdgcn_mfma_f32_16x16x32_bf16(af[i], bfg[j], acc[i][j], 0, 0, 0);
    }

    const int rbase = row0 + wm * 64 + ((lane >> 4) << 2);
    const int cbase = col0 + wn * 64 + (lane & 15);
#pragma unroll
    for (int i = 0; i < 4; ++i) {
#pragma unroll
        for (int j = 0; j < 4; ++j) {
            const int cg = cbase + j * 16;
            float dv = (MODE == 2) ? Dv[cg] : 0.f;
#pragma unroll
            for (int q = 0; q < 4; ++q) {
                const int rg = rbase + i * 16 + q;
                const size_t off = (size_t)rg * N + cg;
                float v = acc[i][j][q];
                if (MODE == 2) {
                    ((float*)Cout)[off] = v + resid[off] * dv;
                } else {
                    ((unsigned short*)Cout)[off] = f2bf(v);
                }
            }
        }
    }
}

// ---------------------------------------------------------------------------
// Causal depthwise conv (K=4) + bias + silu. fp32 in, hi/lo bf16 out.
// ---------------------------------------------------------------------------
__global__ __launch_bounds__(256) void conv_silu_kernel(
    const float* __restrict__ x, const float* __restrict__ w,
    const float* __restrict__ cb, unsigned short* __restrict__ yh,
    unsigned short* __restrict__ yl)
{
    int idx = blockIdx.x * 256 + threadIdx.x;
    if (idx >= MM * HH) return;
    int h  = idx % HH;
    int ml = idx / HH;
    int l  = ml % LL;
    float acc = cb[h];
#pragma unroll
    for (int j = 0; j < KK; ++j) {
        int d = (KK - 1) - j;
        if (l - d >= 0) acc = fmaf(x[(size_t)(ml - d) * HH + h], w[h * KK + j], acc);
    }
    float y = acc * sigmoid_fast(acc);
    split_bf(y, yh[idx], yl[idx]);
}

// ---------------------------------------------------------------------------
// Chunked scan. heads_rt (M,768) fp32: [Rpre|Thpre]. heads_inj (M,384) bf16.
// bu (M,768) bf16: [Re|Im]. states (M,768) bf16 out.
// ---------------------------------------------------------------------------
__global__ __launch_bounds__(256) void scan_chunk_kernel(
    const float* __restrict__ heads_rt, const unsigned short* __restrict__ heads_inj,
    const unsigned short* __restrict__ bu,
    const float* __restrict__ r_base, const float* __restrict__ th_base,
    const float* __restrict__ dt_base, const float* __restrict__ inj,
    float4* __restrict__ summA, float4* __restrict__ summB)
{
    int g = blockIdx.x * 256 + threadIdx.x;
    if (g >= NC * NCH) return;
    int t = g % NCH;
    int j = g / NCH;
    int b = t / PP, p = t - b * PP;
    const float rb = r_base[p], tb = th_base[p], il = inj[p];
    const float dt = 0.02f + 0.98f * sigmoid_fast(dt_base[p]);
    float m00 = 1.f, m01 = 0.f, m10 = 0.f, m11 = 1.f;
    float vzR = 0.f, vxR = 0.f, vzI = 0.f, vxI = 0.f;
    const int mbase = b * LL + j * CLEN;
    for (int l = 0; l < CLEN; ++l) {
        const size_t m = (size_t)(mbase + l);
        const float Rp = heads_rt[m * 768 + p];
        const float Tp = heads_rt[m * 768 + 384 + p];
        const float Ip = bf2f(heads_inj[m * 384 + p]);
        const float b0 = bf2f(bu[m * 768 + p]);
        const float b1 = bf2f(bu[m * 768 + 384 + p]);
        float c0, c1, gdt;
        step_coef(Rp, Tp, Ip, rb, tb, il, dt, c0, c1, gdt);
        const float azR = gdt * b0, azI = gdt * b1;
        float nm00 = c0 * m00 - c1 * m10;
        float nm01 = c0 * m01 - c1 * m11;
        m10 = fmaf(dt, nm00, m10);
        m11 = fmaf(dt, nm01, m11);
        m00 = nm00; m01 = nm01;
        float nvzR = c0 * vzR - c1 * vxR + azR;
        vxR = fmaf(dt, nvzR, vxR); vzR = nvzR;
        float nvzI = c0 * vzI - c1 * vxI + azI;
        vxI = fmaf(dt, nvzI, vxI); vzI = nvzI;
    }
    summA[g] = make_float4(m00, m01, m10, m11);
    summB[g] = make_float4(vzR, vxR, vzI, vxI);
}

__global__ __launch_bounds__(256) void scan_mid_kernel(
    const float4* __restrict__ summA, const float4* __restrict__ summB,
    float4* __restrict__ starts)
{
    int t = blockIdx.x * 256 + threadIdx.x;
    if (t >= NCH) return;
    float zR = 0.f, xR = 0.f, zI = 0.f, xI = 0.f;
    for (int j = 0; j < NC; ++j) {
        starts[j * NCH + t] = make_float4(zR, xR, zI, xI);
        float4 Mv = summA[j * NCH + t];
        float4 Vv = summB[j * NCH + t];
        float nzR = Mv.x * zR + Mv.y * xR + Vv.x;
        float nxR = Mv.z * zR + Mv.w * xR + Vv.y;
        float nzI = Mv.x * zI + Mv.y * xI + Vv.z;
        float nxI = Mv.z * zI + Mv.w * xI + Vv.w;
        zR = nzR; xR = nxR; zI = nzI; xI = nxI;
    }
}

__global__ __launch_bounds__(256) void scan_apply_kernel(
    const float* __restrict__ heads_rt, const unsigned short* __restrict__ heads_inj,
    const unsigned short* __restrict__ bu,
    const float* __restrict__ r_base, const float* __restrict__ th_base,
    const float* __restrict__ dt_base, const float* __restrict__ inj,
    const float4* __restrict__ starts, unsigned short* __restrict__ states)
{
    int g = blockIdx.x * 256 + threadIdx.x;
    if (g >= NC * NCH) return;
    int t = g % NCH;
    int j = g / NCH;
    int b = t / PP, p = t - b * PP;
    const float rb = r_base[p], tb = th_base[p], il = inj[p];
    const float dt = 0.02f + 0.98f * sigmoid_fast(dt_base[p]);
    float4 s0 = starts[j * NCH + t];
    float zR = s0.x, xR = s0.y, zI = s0.z, xI = s0.w;
    const int mbase = b * LL + j * CLEN;
    for (int l = 0; l < CLEN; ++l) {
        const size_t m = (size_t)(mbase + l);
        const float Rp = heads_rt[m * 768 + p];
        const float Tp = heads_rt[m * 768 + 384 + p];
        const float Ip = bf2f(heads_inj[m * 384 + p]);
        const float b0 = bf2f(bu[m * 768 + p]);
        const float b1 = bf2f(bu[m * 768 + 384 + p]);
        float c0, c1, gdt;
        step_coef(Rp, Tp, Ip, rb, tb, il, dt, c0, c1, gdt);
        zR = c0 * zR - c1 * xR + gdt * b0;
        xR = fmaf(dt, zR, xR);
        zI = c0 * zI - c1 * xI + gdt * b1;
        xI = fmaf(dt, zI, xI);
        states[m * 768 + p]       = f2bf(xR);
        states[m * 768 + 384 + p] = f2bf(xI);
    }
}

// ---------------------------------------------------------------------------
extern "C" void kernel_launch(void* const* d_in, const int* in_sizes, int n_in,
                              void* d_out, int out_size, void* d_ws, size_t ws_size,
                              hipStream_t stream)
{
    const float* inputs  = (const float*)d_in[0];
    const float* Wl      = (const float*)d_in[1];
    const float* bl      = (const float*)d_in[2];
    const float* conv_w  = (const float*)d_in[3];
    const float* conv_b  = (const float*)d_in[4];
    const float* Wr      = (const float*)d_in[5];
    const float* Wth     = (const float*)d_in[6];
    const float* Winj    = (const float*)d_in[7];
    const float* r_base  = (const float*)d_in[8];
    const float* th_base = (const float*)d_in[9];
    const float* dt_base = (const float*)d_in[10];
    const float* inj_l   = (const float*)d_in[11];
    const float* Bp      = (const float*)d_in[12];
    const float* Cp      = (const float*)d_in[13];
    const float* Dv      = (const float*)d_in[14];
    float* out = (float*)d_out;

    // ---- workspace layout (lifetime-aliased) ----
    const size_t NB = 768 * 768, NI = 384 * 768, NMH = (size_t)MM * 768;
    unsigned short* wlh    = (unsigned short*)d_ws;
    unsigned short* wll    = wlh + NB;
    unsigned short* wrth_h = wll + NB;
    unsigned short* wrth_l = wrth_h + NB;
    unsigned short* winj   = wrth_l + NB;
    unsigned short* wb     = winj + NI;
    unsigned short* wc     = wb + NB;
    unsigned short* inh    = wc + NB;            // MM*768 bf16, live t2..t5
    unsigned short* inl    = inh + NMH;          // live t2 only -> states later
    unsigned short* f2h    = inl + NMH;          // conv out hi, live t3..t4b
    unsigned short* f2l    = f2h + NMH;          // conv out lo
    unsigned short* hinj   = f2l + NMH;          // heads_inj bf16 MM*384
    float* f1       = (float*)(hinj + (size_t)MM * 384);   // enc out fp32 (96MB)
    float* heads_rt = f1;                        // overlays f1 (dead after conv)
    float4* summA = (float4*)(f1 + NMH);
    float4* summB = summA + (size_t)NC * NCH;
    float4* starts= summB + (size_t)NC * NCH;
    unsigned short* bu = (unsigned short*)d_out; // bf16 MM*768, dead after scan
    unsigned short* states = inl;                // overlays dead inl

    // t1. repack weights + split-convert inputs
    {
        int total = (int)(4 * NB + NI);
        repack_kernel<<<(total + 255) / 256, 256, 0, stream>>>(
            Wl, Wr, Wth, Winj, Bp, Cp, wlh, wll, wrth_h, wrth_l, winj, wb, wc);
        int n4 = (int)(NMH / 4);
        split_convert_kernel<<<(n4 + 255) / 256, 256, 0, stream>>>(inputs, inh, inl, n4);
    }
    // t2. encoder (split): f1 = silu(inputs @ Wl^T + bl)  [fp32]
    mfma_gemm_split<1><<<dim3(768 / 128, MM / 128), 256, 0, stream>>>(
        inh, inl, wlh, wll, f1, 768, bl);
    // t3. conv + silu: f1 -> f2 hi/lo
    conv_silu_kernel<<<(MM * HH + 255) / 256, 256, 0, stream>>>(f1, conv_w, conv_b, f2h, f2l);
    // t4a. R/Th heads (split): heads_rt = f2 @ [Wr;Wth]^T  [fp32, overlays f1]
    mfma_gemm_split<0><<<dim3(768 / 128, MM / 128), 256, 0, stream>>>(
        f2h, f2l, wrth_h, wrth_l, heads_rt, 768, nullptr);
    // t4b. Inj head (plain): hinj = f2h @ Winj^T  [bf16]
    mfma_gemm<3><<<dim3(384 / 128, MM / 128), 256, 0, stream>>>(
        f2h, winj, (void*)hinj, 384, nullptr, nullptr);
    // t5. input projection (plain): bu = inputs @ wb^T  [bf16, in d_out]
    mfma_gemm<3><<<dim3(768 / 128, MM / 128), 256, 0, stream>>>(
        inh, wb, (void*)bu, 768, nullptr, nullptr);
    // t6. chunked scan
    scan_chunk_kernel<<<(NC * NCH) / 256, 256, 0, stream>>>(
        heads_rt, hinj, bu, r_base, th_base, dt_base, inj_l, summA, summB);
    scan_mid_kernel<<<(NCH + 255) / 256, 256, 0, stream>>>(summA, summB, starts);
    scan_apply_kernel<<<(NC * NCH) / 256, 256, 0, stream>>>(
        heads_rt, hinj, bu, r_base, th_base, dt_base, inj_l, starts, states);
    // t7. output projection + residual: out = states @ wc^T + inputs*D  [fp32]
    mfma_gemm<2><<<dim3(768 / 128, MM / 128), 256, 0, stream>>>(
        states, wc, (void*)out, 768, inputs, Dv);
}